// Round 1
// baseline (1337.167 us; speedup 1.0000x reference)
//
#include <hip/hip_runtime.h>
#include <math.h>

#define EPSF 1e-12f

// ---------------------------------------------------------------------------
// Prep: normalize weights (w / sqrt(sum w^2 + EPS)) per cout, transpose 3x3
// weights to [tap][cin][cout] for wave-uniform scalar loads, and compute
// p_eff = (p/10)^2, q_eff = |q|/100.
// params layout: [0:32)=peff1 [32:64)=peff2 [64:96)=peff3 [96]=qe1 [97]=qe2 [98]=qe3
// ---------------------------------------------------------------------------
__global__ __launch_bounds__(256) void prep_kernel(
    const float* __restrict__ w1, const float* __restrict__ p1, const float* __restrict__ q1,
    const float* __restrict__ w2, const float* __restrict__ p2, const float* __restrict__ q2,
    const float* __restrict__ w3, const float* __restrict__ p3, const float* __restrict__ q3,
    float* __restrict__ wn1, float* __restrict__ wn2, float* __restrict__ wn3,
    float* __restrict__ params)
{
    __shared__ float n1[32], n2[32], n3[32];
    const int tid = threadIdx.x;
    if (tid < 32) {
        float s = 0.f;
        for (int i = 0; i < 288; ++i) { float v = w1[tid*288 + i]; s += v*v; }
        n1[tid] = sqrtf(s + EPSF);
    } else if (tid < 64) {
        const int c = tid - 32; float s = 0.f;
        for (int i = 0; i < 288; ++i) { float v = w2[c*288 + i]; s += v*v; }
        n2[c] = sqrtf(s + EPSF);
    } else if (tid < 96) {
        const int c = tid - 64; float s = 0.f;
        for (int i = 0; i < 32; ++i) { float v = w3[c*32 + i]; s += v*v; }
        n3[c] = sqrtf(s + EPSF);
    }
    __syncthreads();
    // wn[(t*32+cin)*32+cout] = w[(cout*32+cin)*9+t] / norm[cout]
    for (int i = tid; i < 9216; i += 256) {
        const int cout = i & 31;
        const int cin  = (i >> 5) & 31;
        const int t    = i >> 10;
        const int src  = (cout*32 + cin)*9 + t;
        wn1[i] = w1[src] / n1[cout];
        wn2[i] = w2[src] / n2[cout];
    }
    for (int i = tid; i < 1024; i += 256) {
        const int cout = i >> 5;
        wn3[i] = w3[i] / n3[cout];
    }
    if (tid < 32) {
        float a1 = p1[tid]*0.1f, a2 = p2[tid]*0.1f, a3 = p3[tid]*0.1f;
        params[tid]      = a1*a1;
        params[32 + tid] = a2*a2;
        params[64 + tid] = a3*a3;
    }
    if (tid == 0) {
        params[96] = fabsf(q1[0])*0.01f;
        params[97] = fabsf(q2[0])*0.01f;
        params[98] = fabsf(q3[0])*0.01f;
    }
}

// ---------------------------------------------------------------------------
// SCS 3x3 conv (pad=1), 32 cin -> 32 cout, input 256x256, fp32.
// Block: 256 threads, 16x16 spatial tile, all 32 couts, one batch n.
// Wave w handles couts [8w, 8w+8); lane -> (col = lane&15, rows 4*(lane>>4)..+3).
// If POOL: fuse 2x2 maxabs pool, write (n,cout,128,128) output.
// ---------------------------------------------------------------------------
template<bool POOL>
__global__ __launch_bounds__(256) void scs3x3_kernel(
    const float* __restrict__ in, const float* __restrict__ wn,
    const float* __restrict__ peff, const float* __restrict__ qeffp,
    float* __restrict__ out)
{
    __shared__ float xs[32*324];   // [cin][18][18]
    __shared__ float ss[324];      // per-pixel sum over cin of x^2

    const int tid   = threadIdx.x;
    const int tileR = blockIdx.x >> 4;
    const int tileC = blockIdx.x & 15;
    const int n     = blockIdx.y;
    const float* xin = in + (size_t)n * 32 * 65536;

    // stage x tile (zero-padded halo of 1)
    for (int i = tid; i < 32*324; i += 256) {
        const int cin = i / 324;
        const int rem = i - cin*324;
        const int ro  = rem / 18;
        const int co  = rem - ro*18;
        const int gr  = tileR*16 + ro - 1;
        const int gc  = tileC*16 + co - 1;
        float v = 0.f;
        if ((unsigned)gr < 256u && (unsigned)gc < 256u)
            v = xin[cin*65536 + gr*256 + gc];
        xs[i] = v;
    }
    __syncthreads();

    // per-position channel sum of squares
    for (int i = tid; i < 324; i += 256) {
        float s = 0.f;
        #pragma unroll
        for (int c = 0; c < 32; ++c) { float v = xs[c*324 + i]; s += v*v; }
        ss[i] = s;
    }
    __syncthreads();

    const int lane    = tid & 63;
    const int col     = lane & 15;
    const int rowBase = (lane >> 4) << 2;
    const int wvu     = __builtin_amdgcn_readfirstlane(tid >> 6); // wave-uniform
    const float* wb   = wn + wvu*8;
    const int xoff    = rowBase*18 + col;

    float acc[8][4];
    #pragma unroll
    for (int j = 0; j < 8; ++j)
        #pragma unroll
        for (int r = 0; r < 4; ++r) acc[j][r] = 0.f;

    for (int cin = 0; cin < 32; ++cin) {
        const float* xp = xs + cin*324 + xoff;
        float xv[6][3];
        #pragma unroll
        for (int ro = 0; ro < 6; ++ro)
            #pragma unroll
            for (int c = 0; c < 3; ++c)
                xv[ro][c] = xp[ro*18 + c];
        const float* wr = wb + cin*32;
        #pragma unroll
        for (int t = 0; t < 9; ++t) {
            const int di = t/3, dj = t - 3*di;
            const float* w8 = wr + t*1024;
            #pragma unroll
            for (int j = 0; j < 8; ++j) {
                const float w = w8[j];     // wave-uniform -> s_load
                #pragma unroll
                for (int r = 0; r < 4; ++r)
                    acc[j][r] = fmaf(xv[r+di][dj], w, acc[j][r]);
            }
        }
    }

    // patch sum-of-squares via row sums of ss
    float rowsum[6];
    #pragma unroll
    for (int ro = 0; ro < 6; ++ro)
        rowsum[ro] = ss[xoff + ro*18] + ss[xoff + ro*18 + 1] + ss[xoff + ro*18 + 2];
    const float qe = qeffp[0];
    float rden[4];
    #pragma unroll
    for (int r = 0; r < 4; ++r) {
        const float sq = rowsum[r] + rowsum[r+1] + rowsum[r+2];
        rden[r] = 1.f / (sqrtf(sq + EPSF) + qe);
    }

    #pragma unroll
    for (int j = 0; j < 8; ++j) {
        const int cout = wvu*8 + j;
        const float pe = peff[cout];
        float res[4];
        #pragma unroll
        for (int r = 0; r < 4; ++r) {
            const float cs = acc[j][r] * rden[r];
            const float m  = __builtin_amdgcn_exp2f(pe * __builtin_amdgcn_logf(fabsf(cs) + EPSF));
            res[r] = copysignf(m, cs);
        }
        if (!POOL) {
            #pragma unroll
            for (int r = 0; r < 4; ++r) {
                const int gr = tileR*16 + rowBase + r;
                const int gc = tileC*16 + col;
                out[(((size_t)n*32 + cout)*256 + gr)*256 + gc] = res[r];
            }
        } else {
            #pragma unroll
            for (int jj = 0; jj < 2; ++jj) {
                const float a = res[2*jj], b = res[2*jj+1];
                float pos = fmaxf(a, b), neg = fmaxf(-a, -b);
                pos = fmaxf(pos, __shfl_xor(pos, 1));
                neg = fmaxf(neg, __shfl_xor(neg, 1));
                const float pooled = (pos >= neg) ? pos : -neg;
                if ((lane & 1) == 0) {
                    const int orow = tileR*8 + (rowBase >> 1) + jj;
                    const int ocol = tileC*8 + (col >> 1);
                    out[(((size_t)n*32 + cout)*128 + orow)*128 + ocol] = pooled;
                }
            }
        }
    }
}

// ---------------------------------------------------------------------------
// Residual branch: maxabs-pool x (2x2), SCS 1x1 conv, out += result.
// One thread per pooled pixel; 2 rows of 128 per block.
// ---------------------------------------------------------------------------
__global__ __launch_bounds__(256) void pool_scs1x1_kernel(
    const float* __restrict__ x, const float* __restrict__ wn3,
    const float* __restrict__ peff, const float* __restrict__ qeffp,
    float* __restrict__ out)
{
    const int tid = threadIdx.x;
    const int col = tid & 127;
    const int row = blockIdx.x*2 + (tid >> 7);
    const int n   = blockIdx.y;

    const float* xb = x + (size_t)n*32*65536 + (size_t)(row*2)*256 + col*2;
    float px[32];
    float sq = 0.f;
    #pragma unroll
    for (int cin = 0; cin < 32; ++cin) {
        const float2 a = *(const float2*)(xb + (size_t)cin*65536);
        const float2 b = *(const float2*)(xb + (size_t)cin*65536 + 256);
        const float pos = fmaxf(fmaxf(a.x, a.y), fmaxf(b.x, b.y));
        const float neg = fmaxf(fmaxf(-a.x, -a.y), fmaxf(-b.x, -b.y));
        const float v = (pos >= neg) ? pos : -neg;
        px[cin] = v;
        sq += v*v;
    }
    const float qe   = qeffp[0];
    const float rden = 1.f / (sqrtf(sq + EPSF) + qe);

    #pragma unroll 4
    for (int cout = 0; cout < 32; ++cout) {
        const float* wr = wn3 + cout*32;   // wave-uniform -> s_load
        float acc = 0.f;
        #pragma unroll
        for (int cin = 0; cin < 32; ++cin)
            acc = fmaf(px[cin], wr[cin], acc);
        const float cs = acc * rden;
        const float m  = __builtin_amdgcn_exp2f(peff[cout] * __builtin_amdgcn_logf(fabsf(cs) + EPSF));
        const float res = copysignf(m, cs);
        const size_t oi = (((size_t)n*32 + cout)*128 + row)*128 + col;
        out[oi] += res;   // adds to pooled h written by scs3x3_kernel<true>
    }
}

// ---------------------------------------------------------------------------
extern "C" void kernel_launch(void* const* d_in, const int* in_sizes, int n_in,
                              void* d_out, int out_size, void* d_ws, size_t ws_size,
                              hipStream_t stream)
{
    const float* x  = (const float*)d_in[0];
    const float* w1 = (const float*)d_in[1];
    const float* p1 = (const float*)d_in[2];
    const float* q1 = (const float*)d_in[3];
    const float* w2 = (const float*)d_in[4];
    const float* p2 = (const float*)d_in[5];
    const float* q2 = (const float*)d_in[6];
    const float* w3 = (const float*)d_in[7];
    const float* p3 = (const float*)d_in[8];
    const float* q3 = (const float*)d_in[9];

    float* ws     = (float*)d_ws;
    float* wn1    = ws;             // 9216
    float* wn2    = ws + 9216;      // 9216
    float* wn3    = ws + 18432;     // 1024
    float* params = ws + 19456;     // 128
    float* h1     = ws + 19584;     // 32*32*256*256 floats (268 MB)

    const size_t need = ((size_t)19584 + (size_t)32*32*256*256) * sizeof(float);
    if (ws_size < need) return;  // fail visibly rather than corrupt memory

    float* out = (float*)d_out;

    prep_kernel<<<1, 256, 0, stream>>>(w1,p1,q1, w2,p2,q2, w3,p3,q3,
                                       wn1, wn2, wn3, params);

    const dim3 grid(256, 32);  // 16x16 tiles, 32 batches
    // layer 1: x -> h1 (full res)
    scs3x3_kernel<false><<<grid, 256, 0, stream>>>(x,  wn1, params,      params+96, h1);
    // layer 2 + maxabs pool: h1 -> out
    scs3x3_kernel<true ><<<grid, 256, 0, stream>>>(h1, wn2, params+32,   params+97, out);
    // residual branch: pool(x) -> 1x1 scs -> out += y
    pool_scs1x1_kernel<<<dim3(64,32), 256, 0, stream>>>(x, wn3, params+64, params+98, out);
}

// Round 3
// 623.633 us; speedup vs baseline: 2.1442x; 2.1442x over previous
//
#include <hip/hip_runtime.h>
#include <math.h>

#define EPSF 1e-12f

typedef _Float16 f16x8 __attribute__((ext_vector_type(8)));
typedef float f32x4 __attribute__((ext_vector_type(4)));

// sign(cs) * (|cs| + EPS)^pe with fast path for pe ~= 2.
__device__ __forceinline__ float fastpow_scs(float cs, float pe) {
    if (__builtin_fabsf(pe - 2.0f) < 1e-4f) {
        return cs * __builtin_fabsf(cs);
    }
    float m = __builtin_amdgcn_exp2f(pe * __builtin_amdgcn_logf(__builtin_fabsf(cs) + EPSF));
    return __builtin_copysignf(m, cs);
}

// ---------------------------------------------------------------------------
// Prep: per-cout weight norms; emit split-fp16 weights (hi + lo, lo = residual)
// in [tap][cout][s(cin)] layout, where s permutes cin so each MFMA lane-group's
// 8 K-elems are contiguous: c = 16h + 4g + j  ->  s = 8g + 4h + j.
// params: [0:32)=peff1 [32:64)=peff2 [64:96)=peff3 [96]=qe1 [97]=qe2 [98]=qe3
// ---------------------------------------------------------------------------
__global__ __launch_bounds__(256) void prep_kernel(
    const float* __restrict__ w1, const float* __restrict__ p1, const float* __restrict__ q1,
    const float* __restrict__ w2, const float* __restrict__ p2, const float* __restrict__ q2,
    const float* __restrict__ w3, const float* __restrict__ p3, const float* __restrict__ q3,
    _Float16* __restrict__ wn1hi, _Float16* __restrict__ wn1lo,
    _Float16* __restrict__ wn2hi, _Float16* __restrict__ wn2lo,
    float* __restrict__ wn3, float* __restrict__ params)
{
    __shared__ float n1[32], n2[32], n3[32];
    const int tid = threadIdx.x;
    if (tid < 32) {
        float s = 0.f;
        for (int i = 0; i < 288; ++i) { float v = w1[tid*288 + i]; s += v*v; }
        n1[tid] = sqrtf(s + EPSF);
    } else if (tid < 64) {
        const int c = tid - 32; float s = 0.f;
        for (int i = 0; i < 288; ++i) { float v = w2[c*288 + i]; s += v*v; }
        n2[c] = sqrtf(s + EPSF);
    } else if (tid < 96) {
        const int c = tid - 64; float s = 0.f;
        for (int i = 0; i < 32; ++i) { float v = w3[c*32 + i]; s += v*v; }
        n3[c] = sqrtf(s + EPSF);
    }
    __syncthreads();
    // i = (t*32 + cout)*32 + s
    for (int i = tid; i < 9216; i += 256) {
        const int s    = i & 31;
        const int cout = (i >> 5) & 31;
        const int t    = i >> 10;
        const int cin  = 16*((s >> 2) & 1) + 4*(s >> 3) + (s & 3);
        const int src  = (cout*32 + cin)*9 + t;
        const float v1 = w1[src] / n1[cout];
        const float v2 = w2[src] / n2[cout];
        const _Float16 h1 = (_Float16)v1;
        const _Float16 h2 = (_Float16)v2;
        wn1hi[i] = h1; wn1lo[i] = (_Float16)(v1 - (float)h1);
        wn2hi[i] = h2; wn2lo[i] = (_Float16)(v2 - (float)h2);
    }
    for (int i = tid; i < 1024; i += 256) {
        const int cout = i >> 5;
        wn3[i] = w3[i] / n3[cout];
    }
    if (tid < 32) {
        float a1 = p1[tid]*0.1f, a2 = p2[tid]*0.1f, a3 = p3[tid]*0.1f;
        params[tid]      = a1*a1;
        params[32 + tid] = a2*a2;
        params[64 + tid] = a3*a3;
    }
    if (tid == 0) {
        params[96] = fabsf(q1[0])*0.01f;
        params[97] = fabsf(q2[0])*0.01f;
        params[98] = fabsf(q3[0])*0.01f;
    }
}

// ---------------------------------------------------------------------------
// SCS 3x3 conv via split-fp16 MFMA (hi+lo, effectively fp32 accuracy).
// 16x16 output tile, 32 cout, 1 batch; 256 threads / 4 waves.
// Wave wv owns output rows 4wv..4wv+3. Per conv: 3 MFMA products
// (ahi*whi + alo*whi + ahi*wlo), lo*lo dropped (~2^-21 relative).
// LDS x-tile planes: [pix=18x18][40 f16] hi and lo (pad -> 2-way banks, free).
// POOL=false: input fp32 NCHW x, output fp32 channel-last h1 [n][pix][s(cout)].
// POOL=true : input fp32 channel-last h1, output fp32 NCHW pooled (128x128).
// ---------------------------------------------------------------------------
template<bool POOL>
__global__ __launch_bounds__(256, 2) void scs3x3_mfma(
    const void* __restrict__ in_,
    const _Float16* __restrict__ wnhi, const _Float16* __restrict__ wnlo,
    const float* __restrict__ peff, const float* __restrict__ qeffp,
    void* __restrict__ out_)
{
    __shared__ alignas(16) _Float16 xh[324*40];
    __shared__ alignas(16) _Float16 xl[324*40];
    __shared__ alignas(16) float ppart[4*324];
    __shared__ alignas(16) float ssum[324];
    __shared__ alignas(16) float rden[256];

    const int tid   = threadIdx.x;
    const int tileR = blockIdx.x >> 4;
    const int tileC = blockIdx.x & 15;
    const int n     = blockIdx.y;

    const int lane = tid & 63;
    const int wv   = tid >> 6;
    const int m16  = lane & 15;
    const int g4   = lane >> 4;

    // resident hi weights: 9 taps x 2 cout-frags, 8 f16 each (K perm-contig)
    f16x8 wh[9][2];
    #pragma unroll
    for (int t = 0; t < 9; ++t)
        #pragma unroll
        for (int cf = 0; cf < 2; ++cf)
            wh[t][cf] = *(const f16x8*)(wnhi + ((t*32 + cf*16 + m16)*32 + g4*8));

    // ---- stage 18x18 halo tile (hi/lo split) + per-pixel sum-of-squares
    if (!POOL) {
        const float* xin = (const float*)in_ + (size_t)n * 32 * 65536;
        for (int i = tid; i < 1296; i += 256) {
            const int g   = i / 324;           // plane-major: coalesced NCHW reads
            const int pix = i - g*324;
            const int ro  = pix / 18;
            const int co  = pix - ro*18;
            const int gr  = tileR*16 + ro - 1;
            const int gc  = tileC*16 + co - 1;
            const bool ok = ((unsigned)gr < 256u) && ((unsigned)gc < 256u);
            float v[8];
            #pragma unroll
            for (int j = 0; j < 4; ++j) {
                v[j]   = ok ? xin[(size_t)(4*g+j)*65536 + gr*256 + gc] : 0.f;
                v[4+j] = ok ? xin[(size_t)(16+4*g+j)*65536 + gr*256 + gc] : 0.f;
            }
            float s = 0.f;
            f16x8 hi, lo;
            #pragma unroll
            for (int j = 0; j < 8; ++j) {
                s += v[j]*v[j];
                hi[j] = (_Float16)v[j];
                lo[j] = (_Float16)(v[j] - (float)hi[j]);
            }
            *(f16x8*)(xh + pix*40 + g*8) = hi;
            *(f16x8*)(xl + pix*40 + g*8) = lo;
            ppart[g*324 + pix] = s;
        }
    } else {
        const float* hin = (const float*)in_ + (size_t)n * 65536 * 32;
        for (int i = tid; i < 1296; i += 256) {
            const int g   = i & 3;             // record-major: 4 lanes = 128B record
            const int pix = i >> 2;
            const int ro  = pix / 18;
            const int co  = pix - ro*18;
            const int gr  = tileR*16 + ro - 1;
            const int gc  = tileC*16 + co - 1;
            const bool ok = ((unsigned)gr < 256u) && ((unsigned)gc < 256u);
            float v[8];
            #pragma unroll
            for (int j = 0; j < 8; ++j) v[j] = 0.f;
            if (ok) {
                const float* rec = hin + (size_t)(gr*256 + gc)*32 + g*8;
                const f32x4 u0 = *(const f32x4*)(rec);
                const f32x4 u1 = *(const f32x4*)(rec + 4);
                #pragma unroll
                for (int j = 0; j < 4; ++j) { v[j] = u0[j]; v[4+j] = u1[j]; }
            }
            float s = 0.f;
            f16x8 hi, lo;
            #pragma unroll
            for (int j = 0; j < 8; ++j) {
                s += v[j]*v[j];
                hi[j] = (_Float16)v[j];
                lo[j] = (_Float16)(v[j] - (float)hi[j]);
            }
            *(f16x8*)(xh + pix*40 + g*8) = hi;
            *(f16x8*)(xl + pix*40 + g*8) = lo;
            ppart[g*324 + pix] = s;
        }
    }
    __syncthreads();
    for (int i = tid; i < 324; i += 256)
        ssum[i] = ppart[i] + ppart[324+i] + ppart[648+i] + ppart[972+i];
    __syncthreads();
    {
        const float qe = qeffp[0];
        const int r = tid >> 4, c = tid & 15;
        float sq = 0.f;
        #pragma unroll
        for (int di = 0; di < 3; ++di)
            #pragma unroll
            for (int dj = 0; dj < 3; ++dj)
                sq += ssum[(r+di)*18 + (c+dj)];
        rden[tid] = 1.f / (sqrtf(sq + EPSF) + qe);
    }
    __syncthreads();

    // ---- K loop: per dj, stream 6 lo-weight frags from global (L1-hot),
    // load 6 shared A-rows (hi+lo), then 3 MFMA product passes.
    f32x4 acc[4][2];
    #pragma unroll
    for (int fr = 0; fr < 4; ++fr)
        #pragma unroll
        for (int cf = 0; cf < 2; ++cf)
            acc[fr][cf] = (f32x4){0.f, 0.f, 0.f, 0.f};

    #pragma unroll
    for (int dj = 0; dj < 3; ++dj) {
        f16x8 wl[3][2];
        #pragma unroll
        for (int di = 0; di < 3; ++di)
            #pragma unroll
            for (int cf = 0; cf < 2; ++cf)
                wl[di][cf] = *(const f16x8*)(wnlo + (((di*3 + dj)*32 + cf*16 + m16)*32 + g4*8));
        f16x8 ah[6], al[6];
        #pragma unroll
        for (int rr = 0; rr < 6; ++rr) {
            const int o = ((4*wv + rr)*18 + m16 + dj)*40 + g4*8;
            ah[rr] = *(const f16x8*)(xh + o);
            al[rr] = *(const f16x8*)(xl + o);
        }
        #pragma unroll
        for (int di = 0; di < 3; ++di)   // pass 1: hi * w_hi
            #pragma unroll
            for (int fr = 0; fr < 4; ++fr)
                #pragma unroll
                for (int cf = 0; cf < 2; ++cf)
                    acc[fr][cf] = __builtin_amdgcn_mfma_f32_16x16x32_f16(
                        ah[fr + di], wh[di*3 + dj][cf], acc[fr][cf], 0, 0, 0);
        #pragma unroll
        for (int di = 0; di < 3; ++di)   // pass 2: lo * w_hi
            #pragma unroll
            for (int fr = 0; fr < 4; ++fr)
                #pragma unroll
                for (int cf = 0; cf < 2; ++cf)
                    acc[fr][cf] = __builtin_amdgcn_mfma_f32_16x16x32_f16(
                        al[fr + di], wh[di*3 + dj][cf], acc[fr][cf], 0, 0, 0);
        #pragma unroll
        for (int di = 0; di < 3; ++di)   // pass 3: hi * w_lo
            #pragma unroll
            for (int fr = 0; fr < 4; ++fr)
                #pragma unroll
                for (int cf = 0; cf < 2; ++cf)
                    acc[fr][cf] = __builtin_amdgcn_mfma_f32_16x16x32_f16(
                        ah[fr + di], wl[di][cf], acc[fr][cf], 0, 0, 0);
    }

    // ---- epilogue: D lane map: cout = cf*16 + (lane&15), col = 4*g4 + reg,
    // row = 4*wv + fr (per-MFMA loop index).
    if (!POOL) {
        float* hout = (float*)out_ + (size_t)n * 65536 * 32;
        #pragma unroll
        for (int cf = 0; cf < 2; ++cf) {
            const int cout = cf*16 + m16;
            const float pe = peff[cout];
            const int sidx = ((m16 >> 2) << 3) + (cf << 2) + (m16 & 3);  // s(cout)
            #pragma unroll
            for (int fr = 0; fr < 4; ++fr) {
                const int r_loc = 4*wv + fr;
                const f32x4 rv = *(const f32x4*)(rden + r_loc*16 + 4*g4);
                const int gr = tileR*16 + r_loc;
                #pragma unroll
                for (int reg = 0; reg < 4; ++reg) {
                    const int gc = tileC*16 + 4*g4 + reg;
                    const float cs = acc[fr][cf][reg] * rv[reg];
                    hout[(size_t)(gr*256 + gc)*32 + sidx] = fastpow_scs(cs, pe);
                }
            }
        }
    } else {
        float* out = (float*)out_;
        #pragma unroll
        for (int cf = 0; cf < 2; ++cf) {
            const int cout = cf*16 + m16;
            const float pe = peff[cout];
            #pragma unroll
            for (int rp = 0; rp < 2; ++rp) {
                const int r0 = 4*wv + 2*rp;
                const f32x4 rv0 = *(const f32x4*)(rden + r0*16 + 4*g4);
                const f32x4 rv1 = *(const f32x4*)(rden + (r0+1)*16 + 4*g4);
                float o2[2];
                #pragma unroll
                for (int cp = 0; cp < 2; ++cp) {
                    const float a0 = acc[2*rp  ][cf][2*cp  ] * rv0[2*cp  ];
                    const float a1 = acc[2*rp  ][cf][2*cp+1] * rv0[2*cp+1];
                    const float b0 = acc[2*rp+1][cf][2*cp  ] * rv1[2*cp  ];
                    const float b1 = acc[2*rp+1][cf][2*cp+1] * rv1[2*cp+1];
                    const float pos = fmaxf(fmaxf(a0, a1), fmaxf(b0, b1));
                    const float neg = fmaxf(fmaxf(-a0, -a1), fmaxf(-b0, -b1));
                    const float pooled = (pos >= neg) ? pos : -neg;
                    o2[cp] = fastpow_scs(pooled, pe);   // pow after pool: monotone+odd
                }
                const int orow = tileR*8 + 2*wv + rp;
                const int ocol = tileC*8 + 2*g4;
                *(float2*)(out + (((size_t)n*32 + cout)*128 + orow)*128 + ocol) =
                    make_float2(o2[0], o2[1]);
            }
        }
    }
}

// ---------------------------------------------------------------------------
// Residual branch: maxabs-pool x (2x2), SCS 1x1 conv (pure fp32), out += result.
// ---------------------------------------------------------------------------
__global__ __launch_bounds__(256) void pool_scs1x1_kernel(
    const float* __restrict__ x, const float* __restrict__ wn3,
    const float* __restrict__ peff, const float* __restrict__ qeffp,
    float* __restrict__ out)
{
    const int tid = threadIdx.x;
    const int col = tid & 127;
    const int row = blockIdx.x*2 + (tid >> 7);
    const int n   = blockIdx.y;

    const float* xb = x + (size_t)n*32*65536 + (size_t)(row*2)*256 + col*2;
    float px[32];
    float sq = 0.f;
    #pragma unroll
    for (int cin = 0; cin < 32; ++cin) {
        const float2 a = *(const float2*)(xb + (size_t)cin*65536);
        const float2 b = *(const float2*)(xb + (size_t)cin*65536 + 256);
        const float pos = fmaxf(fmaxf(a.x, a.y), fmaxf(b.x, b.y));
        const float neg = fmaxf(fmaxf(-a.x, -a.y), fmaxf(-b.x, -b.y));
        const float v = (pos >= neg) ? pos : -neg;
        px[cin] = v;
        sq += v*v;
    }
    const float qe    = qeffp[0];
    const float rdenv = 1.f / (sqrtf(sq + EPSF) + qe);

    #pragma unroll 4
    for (int cout = 0; cout < 32; ++cout) {
        const float* wr = wn3 + cout*32;   // wave-uniform -> s_load
        float acc = 0.f;
        #pragma unroll
        for (int cin = 0; cin < 32; ++cin)
            acc = fmaf(px[cin], wr[cin], acc);
        const float cs = acc * rdenv;
        const float res = fastpow_scs(cs, peff[cout]);
        const size_t oi = (((size_t)n*32 + cout)*128 + row)*128 + col;
        out[oi] += res;   // adds to pooled h written by scs3x3_mfma<true>
    }
}

// ---------------------------------------------------------------------------
extern "C" void kernel_launch(void* const* d_in, const int* in_sizes, int n_in,
                              void* d_out, int out_size, void* d_ws, size_t ws_size,
                              hipStream_t stream)
{
    (void)in_sizes; (void)n_in; (void)out_size;
    const float* x  = (const float*)d_in[0];
    const float* w1 = (const float*)d_in[1];
    const float* p1 = (const float*)d_in[2];
    const float* q1 = (const float*)d_in[3];
    const float* w2 = (const float*)d_in[4];
    const float* p2 = (const float*)d_in[5];
    const float* q2 = (const float*)d_in[6];
    const float* w3 = (const float*)d_in[7];
    const float* p3 = (const float*)d_in[8];
    const float* q3 = (const float*)d_in[9];

    char* wsb = (char*)d_ws;
    _Float16* wn1hi = (_Float16*)(wsb);          // 9216 f16 = 18432 B
    _Float16* wn1lo = (_Float16*)(wsb + 18432);
    _Float16* wn2hi = (_Float16*)(wsb + 36864);
    _Float16* wn2lo = (_Float16*)(wsb + 55296);
    float*    wn3   = (float*)(wsb + 73728);     // 1024 f32 = 4096 B
    float*    params= (float*)(wsb + 77824);     //  128 f32 =  512 B
    float*    h1    = (float*)(wsb + 78336);     // 32*256*256*32 f32 = 268435456 B

    const size_t need = 78336 + (size_t)32*256*256*32*4;
    if (ws_size < need) return;  // fail visibly rather than corrupt memory

    float* out = (float*)d_out;

    prep_kernel<<<1, 256, 0, stream>>>(w1,p1,q1, w2,p2,q2, w3,p3,q3,
                                       wn1hi, wn1lo, wn2hi, wn2lo, wn3, params);

    const dim3 grid(256, 32);  // 16x16 tiles, 32 batches
    // layer 1: x (fp32 NCHW) -> h1 (fp32 channel-last, s-permuted channels)
    scs3x3_mfma<false><<<grid, 256, 0, stream>>>(x,  wn1hi, wn1lo, params,    params+96, h1);
    // layer 2 + maxabs pool: h1 -> out (fp32 NCHW, 128x128)
    scs3x3_mfma<true ><<<grid, 256, 0, stream>>>(h1, wn2hi, wn2lo, params+32, params+97, out);
    // residual branch: pool(x) -> 1x1 scs -> out += y
    pool_scs1x1_kernel<<<dim3(64,32), 256, 0, stream>>>(x, wn3, params+64, params+98, out);
}

// Round 4
// 623.116 us; speedup vs baseline: 2.1459x; 1.0008x over previous
//
#include <hip/hip_runtime.h>
#include <math.h>

#define EPSF 1e-12f

typedef _Float16 f16x8 __attribute__((ext_vector_type(8)));
typedef float f32x4 __attribute__((ext_vector_type(4)));

// sign(cs) * (|cs| + EPS)^pe with fast path for pe ~= 2.
__device__ __forceinline__ float fastpow_scs(float cs, float pe) {
    if (__builtin_fabsf(pe - 2.0f) < 1e-4f) {
        return cs * __builtin_fabsf(cs);
    }
    float m = __builtin_amdgcn_exp2f(pe * __builtin_amdgcn_logf(__builtin_fabsf(cs) + EPSF));
    return __builtin_copysignf(m, cs);
}

__device__ __forceinline__ float h2f(unsigned int bits16) {
    union { unsigned short u; _Float16 h; } z;
    z.u = (unsigned short)bits16;
    return (float)z.h;
}
__device__ __forceinline__ unsigned int packsplit(float v, _Float16& hi16) {
    union { _Float16 h; unsigned short u; } a, b;
    a.h = (_Float16)v;
    b.h = (_Float16)(v - (float)a.h);
    hi16 = a.h;
    return (unsigned int)a.u | ((unsigned int)b.u << 16);
}

// ---------------------------------------------------------------------------
// Prep: per-cout weight norms; split-fp16 weights (hi + residual lo) in
// [tap][cout][k] layout with K-order: k -> cin = 16*(k&1) + (k>>1)
// (so k matches the h1/x record dword order d(cout) = 2*m + h for cout=16h+m).
// params: [0:32)=peff1 [32:64)=peff2 [64:96)=peff3 [96]=qe1 [97]=qe2 [98]=qe3
// ---------------------------------------------------------------------------
__global__ __launch_bounds__(256) void prep_kernel(
    const float* __restrict__ w1, const float* __restrict__ p1, const float* __restrict__ q1,
    const float* __restrict__ w2, const float* __restrict__ p2, const float* __restrict__ q2,
    const float* __restrict__ w3, const float* __restrict__ p3, const float* __restrict__ q3,
    _Float16* __restrict__ wn1hi, _Float16* __restrict__ wn1lo,
    _Float16* __restrict__ wn2hi, _Float16* __restrict__ wn2lo,
    float* __restrict__ wn3, float* __restrict__ params)
{
    __shared__ float n1[32], n2[32], n3[32];
    const int tid = threadIdx.x;
    if (tid < 32) {
        float s = 0.f;
        for (int i = 0; i < 288; ++i) { float v = w1[tid*288 + i]; s += v*v; }
        n1[tid] = sqrtf(s + EPSF);
    } else if (tid < 64) {
        const int c = tid - 32; float s = 0.f;
        for (int i = 0; i < 288; ++i) { float v = w2[c*288 + i]; s += v*v; }
        n2[c] = sqrtf(s + EPSF);
    } else if (tid < 96) {
        const int c = tid - 64; float s = 0.f;
        for (int i = 0; i < 32; ++i) { float v = w3[c*32 + i]; s += v*v; }
        n3[c] = sqrtf(s + EPSF);
    }
    __syncthreads();
    // i = (t*32 + cout)*32 + k
    for (int i = tid; i < 9216; i += 256) {
        const int k    = i & 31;
        const int cout = (i >> 5) & 31;
        const int t    = i >> 10;
        const int cin  = 16*(k & 1) + (k >> 1);
        const int src  = (cout*32 + cin)*9 + t;
        const float v1 = w1[src] / n1[cout];
        const float v2 = w2[src] / n2[cout];
        const _Float16 h1 = (_Float16)v1;
        const _Float16 h2 = (_Float16)v2;
        wn1hi[i] = h1; wn1lo[i] = (_Float16)(v1 - (float)h1);
        wn2hi[i] = h2; wn2lo[i] = (_Float16)(v2 - (float)h2);
    }
    for (int i = tid; i < 1024; i += 256) {
        const int cout = i >> 5;
        wn3[i] = w3[i] / n3[cout];
    }
    if (tid < 32) {
        float a1 = p1[tid]*0.1f, a2 = p2[tid]*0.1f, a3 = p3[tid]*0.1f;
        params[tid]      = a1*a1;
        params[32 + tid] = a2*a2;
        params[64 + tid] = a3*a3;
    }
    if (tid == 0) {
        params[96] = fabsf(q1[0])*0.01f;
        params[97] = fabsf(q2[0])*0.01f;
        params[98] = fabsf(q3[0])*0.01f;
    }
}

// ---------------------------------------------------------------------------
// Shared geometry: 32x16 output tile, halo 34x18 = 612 pixels.
// LDS record per pixel: 128 B = 8 slots of 16 B; slots 0..3 = hi-plane f16x8
// (k-octets), slots 4..7 = lo-plane; physical slot = logical ^ (pix & 7).
// 512 threads = 8 waves; wave wv owns output rows 4wv..4wv+3.
// MFMA lane map (verified r3): m16=lane&15 -> x-col / cout; g4=lane>>4 -> K-octet;
// D: value[reg] at (row=4wv+fr, col=4g4+reg), cout = cf*16+m16.
// ---------------------------------------------------------------------------

#define NPIX 612

__device__ __forceinline__ void kloop_mfma(
    const unsigned int* recs, const _Float16* wnlo,
    const f16x8 wh[9][2], f32x4 acc[4][2],
    int wv, int m16, int g4)
{
    #pragma unroll
    for (int dj = 0; dj < 3; ++dj) {
        f16x8 wl[3][2];
        #pragma unroll
        for (int di = 0; di < 3; ++di)
            #pragma unroll
            for (int cf = 0; cf < 2; ++cf)
                wl[di][cf] = *(const f16x8*)(wnlo + (((di*3 + dj)*32 + cf*16 + m16)*32 + g4*8));
        f16x8 ah[6], al[6];
        #pragma unroll
        for (int rr = 0; rr < 6; ++rr) {
            const int pix = (4*wv + rr)*18 + m16 + dj;
            const int sw  = pix & 7;
            ah[rr] = *(const f16x8*)(recs + pix*32 + ((g4    ) ^ sw)*4);
            al[rr] = *(const f16x8*)(recs + pix*32 + ((4 + g4) ^ sw)*4);
        }
        #pragma unroll
        for (int di = 0; di < 3; ++di)   // pass 1: hi * w_hi
            #pragma unroll
            for (int fr = 0; fr < 4; ++fr)
                #pragma unroll
                for (int cf = 0; cf < 2; ++cf)
                    acc[fr][cf] = __builtin_amdgcn_mfma_f32_16x16x32_f16(
                        ah[fr + di], wh[di*3 + dj][cf], acc[fr][cf], 0, 0, 0);
        #pragma unroll
        for (int di = 0; di < 3; ++di)   // pass 2: lo * w_hi
            #pragma unroll
            for (int fr = 0; fr < 4; ++fr)
                #pragma unroll
                for (int cf = 0; cf < 2; ++cf)
                    acc[fr][cf] = __builtin_amdgcn_mfma_f32_16x16x32_f16(
                        al[fr + di], wh[di*3 + dj][cf], acc[fr][cf], 0, 0, 0);
        #pragma unroll
        for (int di = 0; di < 3; ++di)   // pass 3: hi * w_lo
            #pragma unroll
            for (int fr = 0; fr < 4; ++fr)
                #pragma unroll
                for (int cf = 0; cf < 2; ++cf)
                    acc[fr][cf] = __builtin_amdgcn_mfma_f32_16x16x32_f16(
                        ah[fr + di], wl[di][cf], acc[fr][cf], 0, 0, 0);
    }
}

// ---------------------------------------------------------------------------
// Layer 1: x (fp32 NCHW) -> h1 records (u32 hi|lo per channel, k-order).
// ---------------------------------------------------------------------------
__global__ __launch_bounds__(512, 4) void scs3x3_l1(
    const float* __restrict__ x,
    const _Float16* __restrict__ wnhi, const _Float16* __restrict__ wnlo,
    const float* __restrict__ peff, const float* __restrict__ qeffp,
    unsigned int* __restrict__ h1)
{
    __shared__ alignas(16) unsigned int recs[NPIX*32];
    __shared__ float scratch[NPIX];

    const int tid   = threadIdx.x;
    const int tileR = blockIdx.x >> 4;   // 0..7
    const int tileC = blockIdx.x & 15;   // 0..15
    const int n     = blockIdx.y;
    const int lane  = tid & 63;
    const int wv    = tid >> 6;
    const int m16   = lane & 15;
    const int g4    = lane >> 4;

    f16x8 wh[9][2];
    #pragma unroll
    for (int t = 0; t < 9; ++t)
        #pragma unroll
        for (int cf = 0; cf < 2; ++cf)
            wh[t][cf] = *(const f16x8*)(wnhi + ((t*32 + cf*16 + m16)*32 + g4*8));

    const float* xin = x + (size_t)n * 32 * 65536;

    // ---- stage: thread-per-pixel, 32 channel loads, split + swizzled write
    for (int p = tid; p < NPIX; p += 512) {
        const int ro = p / 18, co = p - ro*18;
        const int gr = tileR*32 + ro - 1;
        const int gc = tileC*16 + co - 1;
        const bool ok = ((unsigned)gr < 256u) && ((unsigned)gc < 256u);
        const int base = gr*256 + gc;
        const int sw = p & 7;
        float s = 0.f;
        #pragma unroll
        for (int G = 0; G < 4; ++G) {
            float v[8];
            #pragma unroll
            for (int j = 0; j < 8; ++j) {
                const int k   = 8*G + j;
                const int cin = 16*(k & 1) + (k >> 1);
                v[j] = ok ? xin[(size_t)cin*65536 + base] : 0.f;
            }
            f16x8 hi, lo;
            #pragma unroll
            for (int j = 0; j < 8; ++j) {
                s += v[j]*v[j];
                hi[j] = (_Float16)v[j];
                lo[j] = (_Float16)(v[j] - (float)hi[j]);
            }
            *(f16x8*)(recs + p*32 + ((G    ) ^ sw)*4) = hi;
            *(f16x8*)(recs + p*32 + ((4 + G) ^ sw)*4) = lo;
        }
        scratch[p] = s;
    }
    __syncthreads();

    // ---- window sums -> rden (per output pixel)
    float rd;
    {
        const int r = tid >> 4, c = tid & 15;
        float sq = 0.f;
        #pragma unroll
        for (int di = 0; di < 3; ++di)
            #pragma unroll
            for (int dc = 0; dc < 3; ++dc)
                sq += scratch[(r + di)*18 + c + dc];
        rd = 1.f / (sqrtf(sq + EPSF) + qeffp[0]);
    }
    __syncthreads();
    scratch[tid] = rd;
    __syncthreads();

    // ---- K loop
    f32x4 acc[4][2];
    #pragma unroll
    for (int fr = 0; fr < 4; ++fr)
        #pragma unroll
        for (int cf = 0; cf < 2; ++cf)
            acc[fr][cf] = (f32x4){0.f, 0.f, 0.f, 0.f};
    kloop_mfma(recs, wnlo, wh, acc, wv, m16, g4);

    // ---- epilogue: res -> packed u32 records (full-line coalesced dwordx2)
    unsigned int* hq = h1 + (size_t)n * 65536 * 32;
    const float pe0 = peff[m16];
    const float pe1 = peff[16 + m16];
    #pragma unroll
    for (int fr = 0; fr < 4; ++fr) {
        const int r_loc = 4*wv + fr;
        const f32x4 rv = *(const f32x4*)(scratch + r_loc*16 + 4*g4);
        const int gr = tileR*32 + r_loc;
        #pragma unroll
        for (int reg = 0; reg < 4; ++reg) {
            const int gc = tileC*16 + 4*g4 + reg;
            _Float16 dummy;
            uint2 pk;
            pk.x = packsplit(fastpow_scs(acc[fr][0][reg] * rv[reg], pe0), dummy);
            pk.y = packsplit(fastpow_scs(acc[fr][1][reg] * rv[reg], pe1), dummy);
            *(uint2*)(hq + (size_t)(gr*256 + gc)*32 + 2*m16) = pk;
        }
    }
}

// ---------------------------------------------------------------------------
// Layer 2 + maxabs pool: h1 records -> out (fp32 NCHW, 128x128).
// ---------------------------------------------------------------------------
__global__ __launch_bounds__(512, 4) void scs3x3_l2(
    const unsigned int* __restrict__ h1,
    const _Float16* __restrict__ wnhi, const _Float16* __restrict__ wnlo,
    const float* __restrict__ peff, const float* __restrict__ qeffp,
    float* __restrict__ out)
{
    __shared__ alignas(16) unsigned int recs[NPIX*32];
    __shared__ float scratch[NPIX];

    const int tid   = threadIdx.x;
    const int tileR = blockIdx.x >> 4;
    const int tileC = blockIdx.x & 15;
    const int n     = blockIdx.y;
    const int lane  = tid & 63;
    const int wv    = tid >> 6;
    const int m16   = lane & 15;
    const int g4    = lane >> 4;

    f16x8 wh[9][2];
    #pragma unroll
    for (int t = 0; t < 9; ++t)
        #pragma unroll
        for (int cf = 0; cf < 2; ++cf)
            wh[t][cf] = *(const f16x8*)(wnhi + ((t*32 + cf*16 + m16)*32 + g4*8));

    const unsigned int* hb = h1 + (size_t)n * 65536 * 32;

    // ---- stage: coalesced chunk copy, bit-split into hi/lo planes (swizzled)
    for (int i = tid; i < NPIX*8; i += 512) {
        const int p = i >> 3, j = i & 7;
        const int ro = p / 18, co = p - ro*18;
        const int gr = tileR*32 + ro - 1;
        const int gc = tileC*16 + co - 1;
        uint4 d = make_uint4(0u, 0u, 0u, 0u);
        if (((unsigned)gr < 256u) && ((unsigned)gc < 256u))
            d = *(const uint4*)(hb + (size_t)(gr*256 + gc)*32 + j*4);
        const unsigned int u0 = (d.x & 0xffffu) | (d.y << 16);
        const unsigned int u1 = (d.z & 0xffffu) | (d.w << 16);
        const unsigned int u2 = (d.x >> 16) | (d.y & 0xffff0000u);
        const unsigned int u3 = (d.z >> 16) | (d.w & 0xffff0000u);
        const int sw = p & 7;
        *(uint2*)(recs + p*32 + (((j >> 1)    ) ^ sw)*4 + (j & 1)*2) = make_uint2(u0, u1);
        *(uint2*)(recs + p*32 + ((4 + (j >> 1)) ^ sw)*4 + (j & 1)*2) = make_uint2(u2, u3);
    }
    __syncthreads();

    // ---- per-pixel sum-of-squares from staged records (swizzle: conflict-free)
    for (int p = tid; p < NPIX; p += 512) {
        const int sw = p & 7;
        float s = 0.f;
        #pragma unroll
        for (int sl = 0; sl < 4; ++sl) {   // hi/lo slot pairs: v = hi + lo
            const uint4 qh = *(const uint4*)(recs + p*32 + ((sl    ) ^ sw)*4);
            const uint4 ql = *(const uint4*)(recs + p*32 + ((4 + sl) ^ sw)*4);
            const unsigned int hs[4] = {qh.x, qh.y, qh.z, qh.w};
            const unsigned int ls[4] = {ql.x, ql.y, ql.z, ql.w};
            #pragma unroll
            for (int e = 0; e < 4; ++e) {
                const float va = h2f(hs[e] & 0xffffu) + h2f(ls[e] & 0xffffu);
                const float vb = h2f(hs[e] >> 16)     + h2f(ls[e] >> 16);
                s += va*va + vb*vb;
            }
        }
        scratch[p] = s;
    }
    __syncthreads();

    float rd;
    {
        const int r = tid >> 4, c = tid & 15;
        float sq = 0.f;
        #pragma unroll
        for (int di = 0; di < 3; ++di)
            #pragma unroll
            for (int dc = 0; dc < 3; ++dc)
                sq += scratch[(r + di)*18 + c + dc];
        rd = 1.f / (sqrtf(sq + EPSF) + qeffp[0]);
    }
    __syncthreads();
    scratch[tid] = rd;
    __syncthreads();

    // ---- K loop
    f32x4 acc[4][2];
    #pragma unroll
    for (int fr = 0; fr < 4; ++fr)
        #pragma unroll
        for (int cf = 0; cf < 2; ++cf)
            acc[fr][cf] = (f32x4){0.f, 0.f, 0.f, 0.f};
    kloop_mfma(recs, wnlo, wh, acc, wv, m16, g4);

    // ---- epilogue: maxabs 2x2 pool (in-thread), pow after pool, NCHW write
    const float pe0 = peff[m16];
    const float pe1 = peff[16 + m16];
    #pragma unroll
    for (int cf = 0; cf < 2; ++cf) {
        const int cout = cf*16 + m16;
        const float pe = cf ? pe1 : pe0;
        #pragma unroll
        for (int rp = 0; rp < 2; ++rp) {
            const int r0 = 4*wv + 2*rp;
            const f32x4 rv0 = *(const f32x4*)(scratch + r0*16 + 4*g4);
            const f32x4 rv1 = *(const f32x4*)(scratch + (r0 + 1)*16 + 4*g4);
            float o2[2];
            #pragma unroll
            for (int cp = 0; cp < 2; ++cp) {
                const float a0 = acc[2*rp    ][cf][2*cp    ] * rv0[2*cp    ];
                const float a1 = acc[2*rp    ][cf][2*cp + 1] * rv0[2*cp + 1];
                const float b0 = acc[2*rp + 1][cf][2*cp    ] * rv1[2*cp    ];
                const float b1 = acc[2*rp + 1][cf][2*cp + 1] * rv1[2*cp + 1];
                const float pos = fmaxf(fmaxf(a0, a1), fmaxf(b0, b1));
                const float neg = fmaxf(fmaxf(-a0, -a1), fmaxf(-b0, -b1));
                const float pooled = (pos >= neg) ? pos : -neg;
                o2[cp] = fastpow_scs(pooled, pe);
            }
            const int orow = tileR*16 + 2*wv + rp;
            const int ocol = tileC*8 + 2*g4;
            *(float2*)(out + (((size_t)n*32 + cout)*128 + orow)*128 + ocol) =
                make_float2(o2[0], o2[1]);
        }
    }
}

// ---------------------------------------------------------------------------
// Residual branch: maxabs-pool x (2x2), SCS 1x1 conv (pure fp32), out += result.
// ---------------------------------------------------------------------------
__global__ __launch_bounds__(256) void pool_scs1x1_kernel(
    const float* __restrict__ x, const float* __restrict__ wn3,
    const float* __restrict__ peff, const float* __restrict__ qeffp,
    float* __restrict__ out)
{
    const int tid = threadIdx.x;
    const int col = tid & 127;
    const int row = blockIdx.x*2 + (tid >> 7);
    const int n   = blockIdx.y;

    const float* xb = x + (size_t)n*32*65536 + (size_t)(row*2)*256 + col*2;
    float px[32];
    float sq = 0.f;
    #pragma unroll
    for (int cin = 0; cin < 32; ++cin) {
        const float2 a = *(const float2*)(xb + (size_t)cin*65536);
        const float2 b = *(const float2*)(xb + (size_t)cin*65536 + 256);
        const float pos = fmaxf(fmaxf(a.x, a.y), fmaxf(b.x, b.y));
        const float neg = fmaxf(fmaxf(-a.x, -a.y), fmaxf(-b.x, -b.y));
        const float v = (pos >= neg) ? pos : -neg;
        px[cin] = v;
        sq += v*v;
    }
    const float qe    = qeffp[0];
    const float rdenv = 1.f / (sqrtf(sq + EPSF) + qe);

    #pragma unroll 4
    for (int cout = 0; cout < 32; ++cout) {
        const float* wr = wn3 + cout*32;   // wave-uniform -> s_load
        float acc = 0.f;
        #pragma unroll
        for (int cin = 0; cin < 32; ++cin)
            acc = fmaf(px[cin], wr[cin], acc);
        const float cs = acc * rdenv;
        const float res = fastpow_scs(cs, peff[cout]);
        const size_t oi = (((size_t)n*32 + cout)*128 + row)*128 + col;
        out[oi] += res;   // adds to pooled h written by scs3x3_l2
    }
}

// ---------------------------------------------------------------------------
extern "C" void kernel_launch(void* const* d_in, const int* in_sizes, int n_in,
                              void* d_out, int out_size, void* d_ws, size_t ws_size,
                              hipStream_t stream)
{
    (void)in_sizes; (void)n_in; (void)out_size;
    const float* x  = (const float*)d_in[0];
    const float* w1 = (const float*)d_in[1];
    const float* p1 = (const float*)d_in[2];
    const float* q1 = (const float*)d_in[3];
    const float* w2 = (const float*)d_in[4];
    const float* p2 = (const float*)d_in[5];
    const float* q2 = (const float*)d_in[6];
    const float* w3 = (const float*)d_in[7];
    const float* p3 = (const float*)d_in[8];
    const float* q3 = (const float*)d_in[9];

    char* wsb = (char*)d_ws;
    _Float16* wn1hi = (_Float16*)(wsb);          // 9216 f16 = 18432 B
    _Float16* wn1lo = (_Float16*)(wsb + 18432);
    _Float16* wn2hi = (_Float16*)(wsb + 36864);
    _Float16* wn2lo = (_Float16*)(wsb + 55296);
    float*    wn3   = (float*)(wsb + 73728);     // 1024 f32 = 4096 B
    float*    params= (float*)(wsb + 77824);     //  128 f32 =  512 B
    unsigned int* h1= (unsigned int*)(wsb + 78336);  // 32*65536*32 u32 = 268435456 B

    const size_t need = 78336 + (size_t)32*65536*32*4;
    if (ws_size < need) return;  // fail visibly rather than corrupt memory

    float* out = (float*)d_out;

    prep_kernel<<<1, 256, 0, stream>>>(w1,p1,q1, w2,p2,q2, w3,p3,q3,
                                       wn1hi, wn1lo, wn2hi, wn2lo, wn3, params);

    const dim3 grid(128, 32);  // 8x16 tiles of 32x16, 32 batches
    scs3x3_l1<<<grid, 512, 0, stream>>>(x,  wn1hi, wn1lo, params,    params+96, h1);
    scs3x3_l2<<<grid, 512, 0, stream>>>(h1, wn2hi, wn2lo, params+32, params+97, out);
    pool_scs1x1_kernel<<<dim3(64,32), 256, 0, stream>>>(x, wn3, params+64, params+98, out);
}

// Round 5
// 606.208 us; speedup vs baseline: 2.2058x; 1.0279x over previous
//
#include <hip/hip_runtime.h>
#include <math.h>

#define EPSF 1e-12f

typedef _Float16 f16x8 __attribute__((ext_vector_type(8)));
typedef float f32x4 __attribute__((ext_vector_type(4)));

// sign(cs) * (|cs| + EPS)^pe with fast path for pe ~= 2.
__device__ __forceinline__ float fastpow_scs(float cs, float pe) {
    if (__builtin_fabsf(pe - 2.0f) < 1e-4f) {
        return cs * __builtin_fabsf(cs);
    }
    float m = __builtin_amdgcn_exp2f(pe * __builtin_amdgcn_logf(__builtin_fabsf(cs) + EPSF));
    return __builtin_copysignf(m, cs);
}

__device__ __forceinline__ float h2f(unsigned int bits16) {
    union { unsigned short u; _Float16 h; } z;
    z.u = (unsigned short)bits16;
    return (float)z.h;
}
__device__ __forceinline__ unsigned int packsplit(float v) {
    union { _Float16 h; unsigned short u; } a, b;
    a.h = (_Float16)v;
    b.h = (_Float16)(v - (float)a.h);
    return (unsigned int)a.u | ((unsigned int)b.u << 16);
}

// ---------------------------------------------------------------------------
// Prep: per-cout weight norms; split-fp16 weights (hi + residual lo) in
// [tap][cout][k] layout, K-order: k -> cin = 16*(k&1) + (k>>1)  (matches the
// h1/x record dword order). wn3k: 1x1 weights in the same k-order, fp32.
// params: [0:32)=peff1 [32:64)=peff2 [64:96)=peff3 [96]=qe1 [97]=qe2 [98]=qe3
// ---------------------------------------------------------------------------
__global__ __launch_bounds__(256) void prep_kernel(
    const float* __restrict__ w1, const float* __restrict__ p1, const float* __restrict__ q1,
    const float* __restrict__ w2, const float* __restrict__ p2, const float* __restrict__ q2,
    const float* __restrict__ w3, const float* __restrict__ p3, const float* __restrict__ q3,
    _Float16* __restrict__ wn1hi, _Float16* __restrict__ wn1lo,
    _Float16* __restrict__ wn2hi, _Float16* __restrict__ wn2lo,
    float* __restrict__ wn3k, float* __restrict__ params)
{
    __shared__ float n1[32], n2[32], n3[32];
    const int tid = threadIdx.x;
    if (tid < 32) {
        float s = 0.f;
        for (int i = 0; i < 288; ++i) { float v = w1[tid*288 + i]; s += v*v; }
        n1[tid] = sqrtf(s + EPSF);
    } else if (tid < 64) {
        const int c = tid - 32; float s = 0.f;
        for (int i = 0; i < 288; ++i) { float v = w2[c*288 + i]; s += v*v; }
        n2[c] = sqrtf(s + EPSF);
    } else if (tid < 96) {
        const int c = tid - 64; float s = 0.f;
        for (int i = 0; i < 32; ++i) { float v = w3[c*32 + i]; s += v*v; }
        n3[c] = sqrtf(s + EPSF);
    }
    __syncthreads();
    // i = (t*32 + cout)*32 + k
    for (int i = tid; i < 9216; i += 256) {
        const int k    = i & 31;
        const int cout = (i >> 5) & 31;
        const int t    = i >> 10;
        const int cin  = 16*(k & 1) + (k >> 1);
        const int src  = (cout*32 + cin)*9 + t;
        const float v1 = w1[src] / n1[cout];
        const float v2 = w2[src] / n2[cout];
        const _Float16 h1v = (_Float16)v1;
        const _Float16 h2v = (_Float16)v2;
        wn1hi[i] = h1v; wn1lo[i] = (_Float16)(v1 - (float)h1v);
        wn2hi[i] = h2v; wn2lo[i] = (_Float16)(v2 - (float)h2v);
    }
    for (int i = tid; i < 1024; i += 256) {
        const int cout = i >> 5;
        const int k    = i & 31;
        const int cin  = 16*(k & 1) + (k >> 1);
        wn3k[i] = w3[cout*32 + cin] / n3[cout];
    }
    if (tid < 32) {
        float a1 = p1[tid]*0.1f, a2 = p2[tid]*0.1f, a3 = p3[tid]*0.1f;
        params[tid]      = a1*a1;
        params[32 + tid] = a2*a2;
        params[64 + tid] = a3*a3;
    }
    if (tid == 0) {
        params[96] = fabsf(q1[0])*0.01f;
        params[97] = fabsf(q2[0])*0.01f;
        params[98] = fabsf(q3[0])*0.01f;
    }
}

// ---------------------------------------------------------------------------
// Shared geometry: 32x16 output tile, halo 34x18 = 612 pixels.
// LDS record per pixel: 128 B = 8 slots of 16 B; slots 0..3 = hi-plane f16x8
// (k-octets), 4..7 = lo-plane; physical slot = logical ^ (pix & 7).
// 512 threads = 8 waves; wave wv owns output rows 4wv..4wv+3.
// MFMA lane map (verified r3/r4): A lane m16 -> pixel-col, g4 -> K-octet;
// D: cout = cf*16+m16, col = 4*g4+reg, row = 4*wv+fr.
// XCD swizzle: tileR = bx&7 (matches HW wg->XCD = linear%8), tileC = bx>>3:
// each XCD owns one full tile-row -> halo/output cache lines shared in-L2.
// ---------------------------------------------------------------------------
#define NPIX 612

// K loop with STREAMED weights (per-dj) to keep VGPRs < 128 (no spills).
// Pass order per dj: (A_hi*W_hi, A_hi*W_lo) then reload A_lo -> A_lo*W_hi.
__device__ __forceinline__ void kloop_mfma(
    const unsigned int* recs,
    const _Float16* __restrict__ wnhi, const _Float16* __restrict__ wnlo,
    f32x4 acc[4][2], int wv, int m16, int g4)
{
    #pragma unroll
    for (int dj = 0; dj < 3; ++dj) {
        f16x8 wh[3][2], wl[3][2];
        #pragma unroll
        for (int di = 0; di < 3; ++di)
            #pragma unroll
            for (int cf = 0; cf < 2; ++cf) {
                const int o = ((di*3 + dj)*32 + cf*16 + m16)*32 + g4*8;
                wh[di][cf] = *(const f16x8*)(wnhi + o);
                wl[di][cf] = *(const f16x8*)(wnlo + o);
            }
        f16x8 a[6];
        #pragma unroll
        for (int rr = 0; rr < 6; ++rr) {
            const int pix = (4*wv + rr)*18 + m16 + dj;
            a[rr] = *(const f16x8*)(recs + pix*32 + ((g4) ^ (pix & 7))*4);
        }
        #pragma unroll
        for (int di = 0; di < 3; ++di)   // A_hi * W_hi
            #pragma unroll
            for (int fr = 0; fr < 4; ++fr)
                #pragma unroll
                for (int cf = 0; cf < 2; ++cf)
                    acc[fr][cf] = __builtin_amdgcn_mfma_f32_16x16x32_f16(
                        a[fr + di], wh[di][cf], acc[fr][cf], 0, 0, 0);
        #pragma unroll
        for (int di = 0; di < 3; ++di)   // A_hi * W_lo
            #pragma unroll
            for (int fr = 0; fr < 4; ++fr)
                #pragma unroll
                for (int cf = 0; cf < 2; ++cf)
                    acc[fr][cf] = __builtin_amdgcn_mfma_f32_16x16x32_f16(
                        a[fr + di], wl[di][cf], acc[fr][cf], 0, 0, 0);
        #pragma unroll
        for (int rr = 0; rr < 6; ++rr) {  // reload lo-plane (reuses a[] regs)
            const int pix = (4*wv + rr)*18 + m16 + dj;
            a[rr] = *(const f16x8*)(recs + pix*32 + ((4 + g4) ^ (pix & 7))*4);
        }
        #pragma unroll
        for (int di = 0; di < 3; ++di)   // A_lo * W_hi
            #pragma unroll
            for (int fr = 0; fr < 4; ++fr)
                #pragma unroll
                for (int cf = 0; cf < 2; ++cf)
                    acc[fr][cf] = __builtin_amdgcn_mfma_f32_16x16x32_f16(
                        a[fr + di], wh[di][cf], acc[fr][cf], 0, 0, 0);
    }
}

// ---------------------------------------------------------------------------
// Layer 1 (fused): x -> h1 records; PLUS residual branch:
// maxabs-pool(x) from LDS records + 1x1 SCS -> out (overwrite).
// ---------------------------------------------------------------------------
__global__ __launch_bounds__(512, 4) void scs3x3_l1(
    const float* __restrict__ x,
    const _Float16* __restrict__ wnhi, const _Float16* __restrict__ wnlo,
    const float* __restrict__ wn3k,
    const float* __restrict__ params,
    unsigned int* __restrict__ h1, float* __restrict__ out)
{
    __shared__ alignas(16) unsigned int recs[NPIX*32];
    __shared__ float scratch[NPIX];

    const int tid   = threadIdx.x;
    const int tileR = blockIdx.x & 7;    // XCD-aligned: all tileC share an XCD
    const int tileC = blockIdx.x >> 3;   // 0..15
    const int n     = blockIdx.y;
    const int lane  = tid & 63;
    const int wv    = tid >> 6;
    const int m16   = lane & 15;
    const int g4    = lane >> 4;

    const float* xin = x + (size_t)n * 32 * 65536;

    // ---- stage: thread-per-pixel, 32 channel loads, split + swizzled write
    for (int p = tid; p < NPIX; p += 512) {
        const int ro = p / 18, co = p - ro*18;
        const int gr = tileR*32 + ro - 1;
        const int gc = tileC*16 + co - 1;
        const bool ok = ((unsigned)gr < 256u) && ((unsigned)gc < 256u);
        const int base = gr*256 + gc;
        const int sw = p & 7;
        float s = 0.f;
        #pragma unroll
        for (int G = 0; G < 4; ++G) {
            float v[8];
            #pragma unroll
            for (int j = 0; j < 8; ++j) {
                const int k   = 8*G + j;
                const int cin = 16*(k & 1) + (k >> 1);
                v[j] = ok ? xin[(size_t)cin*65536 + base] : 0.f;
            }
            f16x8 hi, lo;
            #pragma unroll
            for (int j = 0; j < 8; ++j) {
                s += v[j]*v[j];
                hi[j] = (_Float16)v[j];
                lo[j] = (_Float16)(v[j] - (float)hi[j]);
            }
            *(f16x8*)(recs + p*32 + ((G    ) ^ sw)*4) = hi;
            *(f16x8*)(recs + p*32 + ((4 + G) ^ sw)*4) = lo;
        }
        scratch[p] = s;
    }
    __syncthreads();

    // ---- window sums -> rden (per output pixel)
    float rd;
    {
        const int r = tid >> 4, c = tid & 15;
        float sq = 0.f;
        #pragma unroll
        for (int di = 0; di < 3; ++di)
            #pragma unroll
            for (int dc = 0; dc < 3; ++dc)
                sq += scratch[(r + di)*18 + c + dc];
        rd = 1.f / (sqrtf(sq + EPSF) + params[96]);
    }
    __syncthreads();
    scratch[tid] = rd;
    __syncthreads();

    // ---- K loop
    f32x4 acc[4][2];
    #pragma unroll
    for (int fr = 0; fr < 4; ++fr)
        #pragma unroll
        for (int cf = 0; cf < 2; ++cf)
            acc[fr][cf] = (f32x4){0.f, 0.f, 0.f, 0.f};
    kloop_mfma(recs, wnhi, wnlo, acc, wv, m16, g4);

    // ---- epilogue: packed u32 pair records (coalesced full-line writes)
    {
        unsigned int* hq = h1 + (size_t)n * 65536 * 32;
        const float pe0 = params[m16];
        const float pe1 = params[16 + m16];
        #pragma unroll
        for (int fr = 0; fr < 4; ++fr) {
            const int r_loc = 4*wv + fr;
            const f32x4 rv = *(const f32x4*)(scratch + r_loc*16 + 4*g4);
            const int gr = tileR*32 + r_loc;
            #pragma unroll
            for (int reg = 0; reg < 4; ++reg) {
                const int gc = tileC*16 + 4*g4 + reg;
                uint2 pk;
                pk.x = packsplit(fastpow_scs(acc[fr][0][reg] * rv[reg], pe0));
                pk.y = packsplit(fastpow_scs(acc[fr][1][reg] * rv[reg], pe1));
                *(uint2*)(hq + (size_t)(gr*256 + gc)*32 + 2*m16) = pk;
            }
        }
    }

    // ---- fused residual: maxabs-pool(x) from records + 1x1 SCS -> out
    // records unchanged since stage (no barrier needed). x = hi+lo (~2^-21 exact).
    {
        const int ridx = tid >> 2;   // pooled pixel 0..127 (16 rows x 8 cols)
        const int cg   = tid & 3;    // cout group: 8cg..8cg+7
        const int por  = ridx >> 3;
        const int poc  = ridx & 7;
        const int pr0  = (1 + 2*por)*18 + (1 + 2*poc);
        const int pp[4] = { pr0, pr0 + 1, pr0 + 18, pr0 + 19 };
        float px[32];
        float s3 = 0.f;
        #pragma unroll
        for (int s = 0; s < 4; ++s) {
            uint4 qh[4], ql[4];
            #pragma unroll
            for (int c = 0; c < 4; ++c) {
                const int p = pp[c], sw = p & 7;
                qh[c] = *(const uint4*)(recs + p*32 + ((s    ) ^ sw)*4);
                ql[c] = *(const uint4*)(recs + p*32 + ((4 + s) ^ sw)*4);
            }
            #pragma unroll
            for (int e = 0; e < 4; ++e) {
                float v0[4], v1[4];
                #pragma unroll
                for (int c = 0; c < 4; ++c) {
                    const unsigned int uh = (&qh[c].x)[e];
                    const unsigned int ul = (&ql[c].x)[e];
                    v0[c] = h2f(uh & 0xffffu) + h2f(ul & 0xffffu);
                    v1[c] = h2f(uh >> 16)     + h2f(ul >> 16);
                }
                const float pA = fmaxf(fmaxf(v0[0], v0[1]), fmaxf(v0[2], v0[3]));
                const float nA = fmaxf(fmaxf(-v0[0], -v0[1]), fmaxf(-v0[2], -v0[3]));
                const float pB = fmaxf(fmaxf(v1[0], v1[1]), fmaxf(v1[2], v1[3]));
                const float nB = fmaxf(fmaxf(-v1[0], -v1[1]), fmaxf(-v1[2], -v1[3]));
                const float a = (pA >= nA) ? pA : -nA;
                const float b = (pB >= nB) ? pB : -nB;
                px[8*s + 2*e]     = a;
                px[8*s + 2*e + 1] = b;
                s3 += a*a + b*b;
            }
        }
        const float rd3 = 1.f / (sqrtf(s3 + EPSF) + params[98]);
        const int gor = tileR*16 + por;
        const int goc = tileC*8 + poc;
        float* ob = out + (size_t)n*32*16384 + gor*128 + goc;
        #pragma unroll
        for (int j = 0; j < 8; ++j) {
            const int cout = 8*cg + j;
            const float* wr = wn3k + cout*32;   // k-order, tiny & cache-hot
            float a1 = 0.f;
            #pragma unroll
            for (int k = 0; k < 32; ++k) a1 = fmaf(px[k], wr[k], a1);
            ob[(size_t)cout*16384] = fastpow_scs(a1*rd3, params[64 + cout]);
        }
    }
}

// ---------------------------------------------------------------------------
// Layer 2 + maxabs pool: h1 records -> out += pooled result (fp32 NCHW 128^2).
// ---------------------------------------------------------------------------
__global__ __launch_bounds__(512, 4) void scs3x3_l2(
    const unsigned int* __restrict__ h1,
    const _Float16* __restrict__ wnhi, const _Float16* __restrict__ wnlo,
    const float* __restrict__ peff, const float* __restrict__ qeffp,
    float* __restrict__ out)
{
    __shared__ alignas(16) unsigned int recs[NPIX*32];
    __shared__ float scratch[NPIX];

    const int tid   = threadIdx.x;
    const int tileR = blockIdx.x & 7;
    const int tileC = blockIdx.x >> 3;
    const int n     = blockIdx.y;
    const int lane  = tid & 63;
    const int wv    = tid >> 6;
    const int m16   = lane & 15;
    const int g4    = lane >> 4;

    const unsigned int* hb = h1 + (size_t)n * 65536 * 32;

    // ---- stage: coalesced chunk copy, bit-split into hi/lo planes (swizzled)
    for (int i = tid; i < NPIX*8; i += 512) {
        const int p = i >> 3, j = i & 7;
        const int ro = p / 18, co = p - ro*18;
        const int gr = tileR*32 + ro - 1;
        const int gc = tileC*16 + co - 1;
        uint4 d = make_uint4(0u, 0u, 0u, 0u);
        if (((unsigned)gr < 256u) && ((unsigned)gc < 256u))
            d = *(const uint4*)(hb + (size_t)(gr*256 + gc)*32 + j*4);
        const unsigned int u0 = (d.x & 0xffffu) | (d.y << 16);
        const unsigned int u1 = (d.z & 0xffffu) | (d.w << 16);
        const unsigned int u2 = (d.x >> 16) | (d.y & 0xffff0000u);
        const unsigned int u3 = (d.z >> 16) | (d.w & 0xffff0000u);
        const int sw = p & 7;
        *(uint2*)(recs + p*32 + (((j >> 1)    ) ^ sw)*4 + (j & 1)*2) = make_uint2(u0, u1);
        *(uint2*)(recs + p*32 + ((4 + (j >> 1)) ^ sw)*4 + (j & 1)*2) = make_uint2(u2, u3);
    }
    __syncthreads();

    // ---- per-pixel sum-of-squares from staged records
    for (int p = tid; p < NPIX; p += 512) {
        const int sw = p & 7;
        float s = 0.f;
        #pragma unroll
        for (int sl = 0; sl < 4; ++sl) {
            const uint4 qh = *(const uint4*)(recs + p*32 + ((sl    ) ^ sw)*4);
            const uint4 ql = *(const uint4*)(recs + p*32 + ((4 + sl) ^ sw)*4);
            const unsigned int hs[4] = {qh.x, qh.y, qh.z, qh.w};
            const unsigned int ls[4] = {ql.x, ql.y, ql.z, ql.w};
            #pragma unroll
            for (int e = 0; e < 4; ++e) {
                const float va = h2f(hs[e] & 0xffffu) + h2f(ls[e] & 0xffffu);
                const float vb = h2f(hs[e] >> 16)     + h2f(ls[e] >> 16);
                s += va*va + vb*vb;
            }
        }
        scratch[p] = s;
    }
    __syncthreads();

    float rd;
    {
        const int r = tid >> 4, c = tid & 15;
        float sq = 0.f;
        #pragma unroll
        for (int di = 0; di < 3; ++di)
            #pragma unroll
            for (int dc = 0; dc < 3; ++dc)
                sq += scratch[(r + di)*18 + c + dc];
        rd = 1.f / (sqrtf(sq + EPSF) + qeffp[0]);
    }
    __syncthreads();
    scratch[tid] = rd;
    __syncthreads();

    // ---- K loop
    f32x4 acc[4][2];
    #pragma unroll
    for (int fr = 0; fr < 4; ++fr)
        #pragma unroll
        for (int cf = 0; cf < 2; ++cf)
            acc[fr][cf] = (f32x4){0.f, 0.f, 0.f, 0.f};
    kloop_mfma(recs, wnhi, wnlo, acc, wv, m16, g4);

    // ---- epilogue: maxabs 2x2 pool, pow after pool, out += (residual there)
    const float pe0 = peff[m16];
    const float pe1 = peff[16 + m16];
    #pragma unroll
    for (int cf = 0; cf < 2; ++cf) {
        const int cout = cf*16 + m16;
        const float pe = cf ? pe1 : pe0;
        #pragma unroll
        for (int rp = 0; rp < 2; ++rp) {
            const int r0 = 4*wv + 2*rp;
            const f32x4 rv0 = *(const f32x4*)(scratch + r0*16 + 4*g4);
            const f32x4 rv1 = *(const f32x4*)(scratch + (r0 + 1)*16 + 4*g4);
            float o2[2];
            #pragma unroll
            for (int cp = 0; cp < 2; ++cp) {
                const float a0 = acc[2*rp    ][cf][2*cp    ] * rv0[2*cp    ];
                const float a1 = acc[2*rp    ][cf][2*cp + 1] * rv0[2*cp + 1];
                const float b0 = acc[2*rp + 1][cf][2*cp    ] * rv1[2*cp    ];
                const float b1 = acc[2*rp + 1][cf][2*cp + 1] * rv1[2*cp + 1];
                const float pos = fmaxf(fmaxf(a0, a1), fmaxf(b0, b1));
                const float neg = fmaxf(fmaxf(-a0, -a1), fmaxf(-b0, -b1));
                const float pooled = (pos >= neg) ? pos : -neg;
                o2[cp] = fastpow_scs(pooled, pe);
            }
            const int orow = tileR*16 + 2*wv + rp;
            const int ocol = tileC*8 + 2*g4;
            float2* po = (float2*)(out + (((size_t)n*32 + cout)*128 + orow)*128 + ocol);
            const float2 cur = *po;
            *po = make_float2(cur.x + o2[0], cur.y + o2[1]);
        }
    }
}

// ---------------------------------------------------------------------------
extern "C" void kernel_launch(void* const* d_in, const int* in_sizes, int n_in,
                              void* d_out, int out_size, void* d_ws, size_t ws_size,
                              hipStream_t stream)
{
    (void)in_sizes; (void)n_in; (void)out_size;
    const float* x  = (const float*)d_in[0];
    const float* w1 = (const float*)d_in[1];
    const float* p1 = (const float*)d_in[2];
    const float* q1 = (const float*)d_in[3];
    const float* w2 = (const float*)d_in[4];
    const float* p2 = (const float*)d_in[5];
    const float* q2 = (const float*)d_in[6];
    const float* w3 = (const float*)d_in[7];
    const float* p3 = (const float*)d_in[8];
    const float* q3 = (const float*)d_in[9];

    char* wsb = (char*)d_ws;
    _Float16* wn1hi = (_Float16*)(wsb);          // 9216 f16 = 18432 B
    _Float16* wn1lo = (_Float16*)(wsb + 18432);
    _Float16* wn2hi = (_Float16*)(wsb + 36864);
    _Float16* wn2lo = (_Float16*)(wsb + 55296);
    float*    wn3k  = (float*)(wsb + 73728);     // 1024 f32 = 4096 B
    float*    params= (float*)(wsb + 77824);     //  128 f32 =  512 B
    unsigned int* h1= (unsigned int*)(wsb + 78336);  // 32*65536*32 u32 = 268435456 B

    const size_t need = 78336 + (size_t)32*65536*32*4;
    if (ws_size < need) return;  // fail visibly rather than corrupt memory

    float* out = (float*)d_out;

    prep_kernel<<<1, 256, 0, stream>>>(w1,p1,q1, w2,p2,q2, w3,p3,q3,
                                       wn1hi, wn1lo, wn2hi, wn2lo, wn3k, params);

    const dim3 grid(128, 32);
    // layer 1 + residual branch: x -> h1 records; out = residual(pool(x))
    scs3x3_l1<<<grid, 512, 0, stream>>>(x, wn1hi, wn1lo, wn3k, params, h1, out);
    // layer 2 + maxabs pool: h1 -> out += pooled
    scs3x3_l2<<<grid, 512, 0, stream>>>(h1, wn2hi, wn2lo, params+32, params+97, out);
}

// Round 6
// 502.629 us; speedup vs baseline: 2.6603x; 1.2061x over previous
//
#include <hip/hip_runtime.h>
#include <math.h>

#define EPSF 1e-12f

typedef _Float16 f16x8 __attribute__((ext_vector_type(8)));
typedef float f32x4 __attribute__((ext_vector_type(4)));

// sign(cs) * (|cs| + EPS)^pe with fast path for pe ~= 2.
__device__ __forceinline__ float fastpow_scs(float cs, float pe) {
    if (__builtin_fabsf(pe - 2.0f) < 1e-4f) {
        return cs * __builtin_fabsf(cs);
    }
    float m = __builtin_amdgcn_exp2f(pe * __builtin_amdgcn_logf(__builtin_fabsf(cs) + EPSF));
    return __builtin_copysignf(m, cs);
}

__device__ __forceinline__ float h2f(unsigned int bits16) {
    union { unsigned short u; _Float16 h; } z;
    z.u = (unsigned short)bits16;
    return (float)z.h;
}
// pack fp32 -> u32 (f16 hi | f16 lo<<16), lo = residual
__device__ __forceinline__ unsigned int packsplit(float v) {
    union { _Float16 h; unsigned short u; } a, b;
    a.h = (_Float16)v;
    b.h = (_Float16)(v - (float)a.h);
    return (unsigned int)a.u | ((unsigned int)b.u << 16);
}
// unzip two packed u32 (hi|lo<<16) -> one u32 of the two hi-f16, one of the lo
__device__ __forceinline__ unsigned int perm_hi(unsigned int a, unsigned int b) {
    return __builtin_amdgcn_perm(b, a, 0x05040100u);  // [a.b0,a.b1,b.b0,b.b1]
}
__device__ __forceinline__ unsigned int perm_lo(unsigned int a, unsigned int b) {
    return __builtin_amdgcn_perm(b, a, 0x07060302u);  // [a.b2,a.b3,b.b2,b.b3]
}

// ---------------------------------------------------------------------------
// Prep: per-cout weight norms; split-fp16 weights (hi + residual lo) in
// [tap][cout][k] layout, K-order: k -> cin = 16*(k&1) + (k>>1)  (matches the
// record dword order: dword d holds channel cin(d)). wn3: original cin order.
// params: [0:32)=peff1 [32:64)=peff2 [64:96)=peff3 [96]=qe1 [97]=qe2 [98]=qe3
// ---------------------------------------------------------------------------
__global__ __launch_bounds__(256) void prep_kernel(
    const float* __restrict__ w1, const float* __restrict__ p1, const float* __restrict__ q1,
    const float* __restrict__ w2, const float* __restrict__ p2, const float* __restrict__ q2,
    const float* __restrict__ w3, const float* __restrict__ p3, const float* __restrict__ q3,
    _Float16* __restrict__ wn1hi, _Float16* __restrict__ wn1lo,
    _Float16* __restrict__ wn2hi, _Float16* __restrict__ wn2lo,
    float* __restrict__ wn3, float* __restrict__ params)
{
    __shared__ float n1[32], n2[32], n3[32];
    const int tid = threadIdx.x;
    if (tid < 32) {
        float s = 0.f;
        for (int i = 0; i < 288; ++i) { float v = w1[tid*288 + i]; s += v*v; }
        n1[tid] = sqrtf(s + EPSF);
    } else if (tid < 64) {
        const int c = tid - 32; float s = 0.f;
        for (int i = 0; i < 288; ++i) { float v = w2[c*288 + i]; s += v*v; }
        n2[c] = sqrtf(s + EPSF);
    } else if (tid < 96) {
        const int c = tid - 64; float s = 0.f;
        for (int i = 0; i < 32; ++i) { float v = w3[c*32 + i]; s += v*v; }
        n3[c] = sqrtf(s + EPSF);
    }
    __syncthreads();
    // i = (t*32 + cout)*32 + k
    for (int i = tid; i < 9216; i += 256) {
        const int k    = i & 31;
        const int cout = (i >> 5) & 31;
        const int t    = i >> 10;
        const int cin  = 16*(k & 1) + (k >> 1);
        const int src  = (cout*32 + cin)*9 + t;
        const float v1 = w1[src] / n1[cout];
        const float v2 = w2[src] / n2[cout];
        const _Float16 h1v = (_Float16)v1;
        const _Float16 h2v = (_Float16)v2;
        wn1hi[i] = h1v; wn1lo[i] = (_Float16)(v1 - (float)h1v);
        wn2hi[i] = h2v; wn2lo[i] = (_Float16)(v2 - (float)h2v);
    }
    for (int i = tid; i < 1024; i += 256) {
        const int cout = i >> 5;
        wn3[i] = w3[i] / n3[cout];
    }
    if (tid < 32) {
        float a1 = p1[tid]*0.1f, a2 = p2[tid]*0.1f, a3 = p3[tid]*0.1f;
        params[tid]      = a1*a1;
        params[32 + tid] = a2*a2;
        params[64 + tid] = a3*a3;
    }
    if (tid == 0) {
        params[96] = fabsf(q1[0])*0.01f;
        params[97] = fabsf(q2[0])*0.01f;
        params[98] = fabsf(q3[0])*0.01f;
    }
}

// ---------------------------------------------------------------------------
// Geometry: 16x16 output tile, halo 18x18 = 324 pixels. 512 threads = 8 waves;
// wave wv owns output rows 2wv..2wv+1 (acc[2][2], 16 regs).
// LDS record per pixel: 32 u32 (ch k packed hi|lo<<16) = 8 slots of 16B;
// physical slot = logical ^ (pix & 7)  -> all LDS traffic 2-way (free).
// MFMA lane map (verified r3-r5): A lane m16 -> pixel col, g4 -> K-octet;
// D: cout = cf*16+m16, col = 4*g4+reg, row = 2*wv+fr.
// XCD: tileR = bx&15 -> XCD = bx%8 owns row-bands {r, r+8} (halo L2 locality).
// 3 blocks/CU (LDS 47.7KB), __launch_bounds__(512,6) caps VGPR at 85.
// ---------------------------------------------------------------------------
#define NPIX 324

// K loop: per (dj,di): stream 4 weight frags + 2 pixel records (unzip via
// v_perm), 12 MFMAs (3 split passes x 2 rows x 2 cout-frags).
__device__ __forceinline__ void kloop_mfma(
    const unsigned int* recs,
    const _Float16* __restrict__ wnhi, const _Float16* __restrict__ wnlo,
    f32x4 acc[2][2], int wv, int m16, int g4)
{
    #pragma unroll
    for (int dj = 0; dj < 3; ++dj) {
        #pragma unroll
        for (int di = 0; di < 3; ++di) {
            f16x8 wh[2], wl[2];
            #pragma unroll
            for (int cf = 0; cf < 2; ++cf) {
                const int o = ((di*3 + dj)*32 + cf*16 + m16)*32 + g4*8;
                wh[cf] = *(const f16x8*)(wnhi + o);
                wl[cf] = *(const f16x8*)(wnlo + o);
            }
            f16x8 ah[2], al[2];
            #pragma unroll
            for (int fr = 0; fr < 2; ++fr) {
                const int pix = (2*wv + di + fr)*18 + m16 + dj;
                const int sw  = pix & 7;
                const uint4 r0 = *(const uint4*)(recs + pix*32 + ((2*g4    ) ^ sw)*4);
                const uint4 r1 = *(const uint4*)(recs + pix*32 + ((2*g4 + 1) ^ sw)*4);
                uint4 h, l;
                h.x = perm_hi(r0.x, r0.y); l.x = perm_lo(r0.x, r0.y);
                h.y = perm_hi(r0.z, r0.w); l.y = perm_lo(r0.z, r0.w);
                h.z = perm_hi(r1.x, r1.y); l.z = perm_lo(r1.x, r1.y);
                h.w = perm_hi(r1.z, r1.w); l.w = perm_lo(r1.z, r1.w);
                ah[fr] = *(const f16x8*)&h;
                al[fr] = *(const f16x8*)&l;
            }
            #pragma unroll
            for (int fr = 0; fr < 2; ++fr)
                #pragma unroll
                for (int cf = 0; cf < 2; ++cf) {
                    acc[fr][cf] = __builtin_amdgcn_mfma_f32_16x16x32_f16(
                        ah[fr], wh[cf], acc[fr][cf], 0, 0, 0);
                    acc[fr][cf] = __builtin_amdgcn_mfma_f32_16x16x32_f16(
                        al[fr], wh[cf], acc[fr][cf], 0, 0, 0);
                    acc[fr][cf] = __builtin_amdgcn_mfma_f32_16x16x32_f16(
                        ah[fr], wl[cf], acc[fr][cf], 0, 0, 0);
                }
        }
    }
}

// ---------------------------------------------------------------------------
// Layer 1: x (fp32 NCHW) -> h1 packed records.
// ---------------------------------------------------------------------------
__global__ __launch_bounds__(512, 6) void scs3x3_l1(
    const float* __restrict__ x,
    const _Float16* __restrict__ wnhi, const _Float16* __restrict__ wnlo,
    const float* __restrict__ peff, const float* __restrict__ qeffp,
    unsigned int* __restrict__ h1)
{
    __shared__ alignas(16) unsigned int recs[NPIX*32];   // 41472 B
    __shared__ float scratch4[4*NPIX];                   //  5184 B
    __shared__ float rden[256];                          //  1024 B

    const int tid   = threadIdx.x;
    const int tileR = blockIdx.x & 15;
    const int tileC = blockIdx.x >> 4;
    const int n     = blockIdx.y;
    const int lane  = tid & 63;
    const int wv    = tid >> 6;
    const int m16   = lane & 15;
    const int g4    = lane >> 4;

    const float* xin = x + (size_t)n * 32 * 65536;

    // ---- stage: (pixel, ch-octet) per slot-thread; split fp32 -> packed u32
    for (int i = tid; i < 4*NPIX; i += 512) {
        const int p = i >> 2, q = i & 3;
        const int ro = p / 18, co = p - ro*18;
        const int gr = tileR*16 + ro - 1;
        const int gc = tileC*16 + co - 1;
        const bool ok = ((unsigned)gr < 256u) && ((unsigned)gc < 256u);
        const int base = gr*256 + gc;
        float s = 0.f;
        unsigned int pk[8];
        #pragma unroll
        for (int j = 0; j < 8; ++j) {
            const int k   = 8*q + j;
            const int cin = 16*(k & 1) + (k >> 1);
            const float v = ok ? xin[(size_t)cin*65536 + base] : 0.f;
            s += v*v;
            pk[j] = packsplit(v);
        }
        const int sw = p & 7;
        *(uint4*)(recs + p*32 + ((2*q    ) ^ sw)*4) = make_uint4(pk[0], pk[1], pk[2], pk[3]);
        *(uint4*)(recs + p*32 + ((2*q + 1) ^ sw)*4) = make_uint4(pk[4], pk[5], pk[6], pk[7]);
        scratch4[q*NPIX + p] = s;
    }
    __syncthreads();

    // ---- window sums -> rden
    if (tid < 256) {
        const int r = tid >> 4, c = tid & 15;
        float sq = 0.f;
        #pragma unroll
        for (int di = 0; di < 3; ++di)
            #pragma unroll
            for (int dc = 0; dc < 3; ++dc) {
                const int p = (r + di)*18 + c + dc;
                sq += scratch4[p] + scratch4[NPIX + p] + scratch4[2*NPIX + p] + scratch4[3*NPIX + p];
            }
        rden[tid] = 1.f / (sqrtf(sq + EPSF) + qeffp[0]);
    }
    __syncthreads();

    // ---- K loop
    f32x4 acc[2][2];
    #pragma unroll
    for (int fr = 0; fr < 2; ++fr)
        #pragma unroll
        for (int cf = 0; cf < 2; ++cf)
            acc[fr][cf] = (f32x4){0.f, 0.f, 0.f, 0.f};
    kloop_mfma(recs, wnhi, wnlo, acc, wv, m16, g4);

    // ---- epilogue: pow + packed record write (uint2: couts m16, m16+16)
    unsigned int* hq = h1 + (size_t)n * 65536 * 32;
    const float pe0 = peff[m16];
    const float pe1 = peff[16 + m16];
    #pragma unroll
    for (int fr = 0; fr < 2; ++fr) {
        const int r_loc = 2*wv + fr;
        const f32x4 rv = *(const f32x4*)(rden + r_loc*16 + 4*g4);
        const int gr = tileR*16 + r_loc;
        #pragma unroll
        for (int reg = 0; reg < 4; ++reg) {
            const int gc = tileC*16 + 4*g4 + reg;
            uint2 pk;
            pk.x = packsplit(fastpow_scs(acc[fr][0][reg] * rv[reg], pe0));
            pk.y = packsplit(fastpow_scs(acc[fr][1][reg] * rv[reg], pe1));
            *(uint2*)(hq + (size_t)(gr*256 + gc)*32 + 2*m16) = pk;
        }
    }
}

// ---------------------------------------------------------------------------
// Layer 2 + maxabs pool: h1 records -> out += pooled result (fp32 NCHW 128^2).
// Stage is a pure coalesced uint4 copy; s recomputed from packed values.
// ---------------------------------------------------------------------------
__global__ __launch_bounds__(512, 6) void scs3x3_l2(
    const unsigned int* __restrict__ h1,
    const _Float16* __restrict__ wnhi, const _Float16* __restrict__ wnlo,
    const float* __restrict__ peff, const float* __restrict__ qeffp,
    float* __restrict__ out)
{
    __shared__ alignas(16) unsigned int recs[NPIX*32];
    __shared__ float scratch4[4*NPIX];
    __shared__ float rden[256];

    const int tid   = threadIdx.x;
    const int tileR = blockIdx.x & 15;
    const int tileC = blockIdx.x >> 4;
    const int n     = blockIdx.y;
    const int lane  = tid & 63;
    const int wv    = tid >> 6;
    const int m16   = lane & 15;
    const int g4    = lane >> 4;

    const unsigned int* hb = h1 + (size_t)n * 65536 * 32;

    // ---- stage: coalesced copy + s from packed (hi+lo reconstruct)
    for (int i = tid; i < 4*NPIX; i += 512) {
        const int p = i >> 2, q = i & 3;
        const int ro = p / 18, co = p - ro*18;
        const int gr = tileR*16 + ro - 1;
        const int gc = tileC*16 + co - 1;
        uint4 d0 = make_uint4(0u,0u,0u,0u), d1 = make_uint4(0u,0u,0u,0u);
        if (((unsigned)gr < 256u) && ((unsigned)gc < 256u)) {
            const unsigned int* rec = hb + (size_t)(gr*256 + gc)*32 + 8*q;
            d0 = *(const uint4*)(rec);
            d1 = *(const uint4*)(rec + 4);
        }
        float s = 0.f;
        const unsigned int us[8] = {d0.x,d0.y,d0.z,d0.w,d1.x,d1.y,d1.z,d1.w};
        #pragma unroll
        for (int j = 0; j < 8; ++j) {
            const float v = h2f(us[j] & 0xffffu) + h2f(us[j] >> 16);
            s += v*v;
        }
        const int sw = p & 7;
        *(uint4*)(recs + p*32 + ((2*q    ) ^ sw)*4) = d0;
        *(uint4*)(recs + p*32 + ((2*q + 1) ^ sw)*4) = d1;
        scratch4[q*NPIX + p] = s;
    }
    __syncthreads();

    if (tid < 256) {
        const int r = tid >> 4, c = tid & 15;
        float sq = 0.f;
        #pragma unroll
        for (int di = 0; di < 3; ++di)
            #pragma unroll
            for (int dc = 0; dc < 3; ++dc) {
                const int p = (r + di)*18 + c + dc;
                sq += scratch4[p] + scratch4[NPIX + p] + scratch4[2*NPIX + p] + scratch4[3*NPIX + p];
            }
        rden[tid] = 1.f / (sqrtf(sq + EPSF) + qeffp[0]);
    }
    __syncthreads();

    // ---- K loop
    f32x4 acc[2][2];
    #pragma unroll
    for (int fr = 0; fr < 2; ++fr)
        #pragma unroll
        for (int cf = 0; cf < 2; ++cf)
            acc[fr][cf] = (f32x4){0.f, 0.f, 0.f, 0.f};
    kloop_mfma(recs, wnhi, wnlo, acc, wv, m16, g4);

    // ---- epilogue: 2x2 maxabs pool (rows fr=0,1; col pairs), pow, out +=
    const float pe0 = peff[m16];
    const float pe1 = peff[16 + m16];
    const f32x4 rv0 = *(const f32x4*)(rden + (2*wv    )*16 + 4*g4);
    const f32x4 rv1 = *(const f32x4*)(rden + (2*wv + 1)*16 + 4*g4);
    const int orow = tileR*8 + wv;
    const int ocol = tileC*8 + 2*g4;
    #pragma unroll
    for (int cf = 0; cf < 2; ++cf) {
        const int cout = cf*16 + m16;
        const float pe = cf ? pe1 : pe0;
        float o2[2];
        #pragma unroll
        for (int cp = 0; cp < 2; ++cp) {
            const float a0 = acc[0][cf][2*cp    ] * rv0[2*cp    ];
            const float a1 = acc[0][cf][2*cp + 1] * rv0[2*cp + 1];
            const float b0 = acc[1][cf][2*cp    ] * rv1[2*cp    ];
            const float b1 = acc[1][cf][2*cp + 1] * rv1[2*cp + 1];
            const float pos = fmaxf(fmaxf(a0, a1), fmaxf(b0, b1));
            const float neg = fmaxf(fmaxf(-a0, -a1), fmaxf(-b0, -b1));
            const float pooled = (pos >= neg) ? pos : -neg;
            o2[cp] = fastpow_scs(pooled, pe);
        }
        float2* po = (float2*)(out + (((size_t)n*32 + cout)*128 + orow)*128 + ocol);
        const float2 cur = *po;
        *po = make_float2(cur.x + o2[0], cur.y + o2[1]);
    }
}

// ---------------------------------------------------------------------------
// Residual branch: maxabs-pool x (2x2), SCS 1x1 conv (pure fp32), out = result.
// ---------------------------------------------------------------------------
__global__ __launch_bounds__(256) void pool_scs1x1_kernel(
    const float* __restrict__ x, const float* __restrict__ wn3,
    const float* __restrict__ peff, const float* __restrict__ qeffp,
    float* __restrict__ out)
{
    const int tid = threadIdx.x;
    const int col = tid & 127;
    const int row = blockIdx.x*2 + (tid >> 7);
    const int n   = blockIdx.y;

    const float* xb = x + (size_t)n*32*65536 + (size_t)(row*2)*256 + col*2;
    float px[32];
    float sq = 0.f;
    #pragma unroll
    for (int cin = 0; cin < 32; ++cin) {
        const float2 a = *(const float2*)(xb + (size_t)cin*65536);
        const float2 b = *(const float2*)(xb + (size_t)cin*65536 + 256);
        const float pos = fmaxf(fmaxf(a.x, a.y), fmaxf(b.x, b.y));
        const float neg = fmaxf(fmaxf(-a.x, -a.y), fmaxf(-b.x, -b.y));
        const float v = (pos >= neg) ? pos : -neg;
        px[cin] = v;
        sq += v*v;
    }
    const float qe    = qeffp[0];
    const float rdenv = 1.f / (sqrtf(sq + EPSF) + qe);

    #pragma unroll 4
    for (int cout = 0; cout < 32; ++cout) {
        const float* wr = wn3 + cout*32;   // wave-uniform -> s_load
        float acc = 0.f;
        #pragma unroll
        for (int cin = 0; cin < 32; ++cin)
            acc = fmaf(px[cin], wr[cin], acc);
        const float cs = acc * rdenv;
        const float res = fastpow_scs(cs, peff[cout]);
        const size_t oi = (((size_t)n*32 + cout)*128 + row)*128 + col;
        out[oi] = res;   // overwrite; scs3x3_l2 adds the main path afterwards
    }
}

// ---------------------------------------------------------------------------
extern "C" void kernel_launch(void* const* d_in, const int* in_sizes, int n_in,
                              void* d_out, int out_size, void* d_ws, size_t ws_size,
                              hipStream_t stream)
{
    (void)in_sizes; (void)n_in; (void)out_size;
    const float* x  = (const float*)d_in[0];
    const float* w1 = (const float*)d_in[1];
    const float* p1 = (const float*)d_in[2];
    const float* q1 = (const float*)d_in[3];
    const float* w2 = (const float*)d_in[4];
    const float* p2 = (const float*)d_in[5];
    const float* q2 = (const float*)d_in[6];
    const float* w3 = (const float*)d_in[7];
    const float* p3 = (const float*)d_in[8];
    const float* q3 = (const float*)d_in[9];

    char* wsb = (char*)d_ws;
    _Float16* wn1hi = (_Float16*)(wsb);          // 9216 f16 = 18432 B
    _Float16* wn1lo = (_Float16*)(wsb + 18432);
    _Float16* wn2hi = (_Float16*)(wsb + 36864);
    _Float16* wn2lo = (_Float16*)(wsb + 55296);
    float*    wn3   = (float*)(wsb + 73728);     // 1024 f32 = 4096 B
    float*    params= (float*)(wsb + 77824);     //  128 f32 =  512 B
    unsigned int* h1= (unsigned int*)(wsb + 78336);  // 32*65536*32 u32 = 268435456 B

    const size_t need = 78336 + (size_t)32*65536*32*4;
    if (ws_size < need) return;  // fail visibly rather than corrupt memory

    float* out = (float*)d_out;

    prep_kernel<<<1, 256, 0, stream>>>(w1,p1,q1, w2,p2,q2, w3,p3,q3,
                                       wn1hi, wn1lo, wn2hi, wn2lo, wn3, params);

    const dim3 grid(256, 32);   // 16x16 tiles of 16x16, 32 batches
    // layer 1: x -> h1 packed records
    scs3x3_l1<<<grid, 512, 0, stream>>>(x, wn1hi, wn1lo, params, params+96, h1);
    // residual branch: pool(x) -> 1x1 scs -> out  (overwrite)
    pool_scs1x1_kernel<<<dim3(64,32), 256, 0, stream>>>(x, wn3, params+64, params+98, out);
    // layer 2 + maxabs pool: h1 -> out += pooled
    scs3x3_l2<<<grid, 512, 0, stream>>>(h1, wn2hi, wn2lo, params+32, params+97, out);
}

// Round 7
// 486.943 us; speedup vs baseline: 2.7460x; 1.0322x over previous
//
#include <hip/hip_runtime.h>
#include <math.h>

#define EPSF 1e-12f

typedef _Float16 f16x8 __attribute__((ext_vector_type(8)));
typedef float f32x4 __attribute__((ext_vector_type(4)));

// sign(cs) * (|cs| + EPS)^pe with fast path for pe ~= 2.
__device__ __forceinline__ float fastpow_scs(float cs, float pe) {
    if (__builtin_fabsf(pe - 2.0f) < 1e-4f) {
        return cs * __builtin_fabsf(cs);
    }
    float m = __builtin_amdgcn_exp2f(pe * __builtin_amdgcn_logf(__builtin_fabsf(cs) + EPSF));
    return __builtin_copysignf(m, cs);
}

__device__ __forceinline__ float h2f(unsigned int bits16) {
    union { unsigned short u; _Float16 h; } z;
    z.u = (unsigned short)bits16;
    return (float)z.h;
}
// pack fp32 -> u32 (f16 hi | f16 lo<<16), lo = residual
__device__ __forceinline__ unsigned int packsplit(float v) {
    union { _Float16 h; unsigned short u; } a, b;
    a.h = (_Float16)v;
    b.h = (_Float16)(v - (float)a.h);
    return (unsigned int)a.u | ((unsigned int)b.u << 16);
}
// unzip two packed u32 (hi|lo<<16) -> one u32 of the two hi-f16, one of the lo
__device__ __forceinline__ unsigned int perm_hi(unsigned int a, unsigned int b) {
    return __builtin_amdgcn_perm(b, a, 0x05040100u);  // [a.b0,a.b1,b.b0,b.b1]
}
__device__ __forceinline__ unsigned int perm_lo(unsigned int a, unsigned int b) {
    return __builtin_amdgcn_perm(b, a, 0x07060302u);  // [a.b2,a.b3,b.b2,b.b3]
}

// ---------------------------------------------------------------------------
// Prep: per-cout weight norms; split-fp16 weights (hi + residual lo) in
// [tap][cout][k] layout, K-order: k -> cin = 16*(k&1) + (k>>1)  (matches the
// record dword order: dword d holds channel cin(d)). wn3: original cin order.
// params: [0:32)=peff1 [32:64)=peff2 [64:96)=peff3 [96]=qe1 [97]=qe2 [98]=qe3
// ---------------------------------------------------------------------------
__global__ __launch_bounds__(256) void prep_kernel(
    const float* __restrict__ w1, const float* __restrict__ p1, const float* __restrict__ q1,
    const float* __restrict__ w2, const float* __restrict__ p2, const float* __restrict__ q2,
    const float* __restrict__ w3, const float* __restrict__ p3, const float* __restrict__ q3,
    _Float16* __restrict__ wn1hi, _Float16* __restrict__ wn1lo,
    _Float16* __restrict__ wn2hi, _Float16* __restrict__ wn2lo,
    float* __restrict__ wn3, float* __restrict__ params)
{
    __shared__ float n1[32], n2[32], n3[32];
    const int tid = threadIdx.x;
    if (tid < 32) {
        float s = 0.f;
        for (int i = 0; i < 288; ++i) { float v = w1[tid*288 + i]; s += v*v; }
        n1[tid] = sqrtf(s + EPSF);
    } else if (tid < 64) {
        const int c = tid - 32; float s = 0.f;
        for (int i = 0; i < 288; ++i) { float v = w2[c*288 + i]; s += v*v; }
        n2[c] = sqrtf(s + EPSF);
    } else if (tid < 96) {
        const int c = tid - 64; float s = 0.f;
        for (int i = 0; i < 32; ++i) { float v = w3[c*32 + i]; s += v*v; }
        n3[c] = sqrtf(s + EPSF);
    }
    __syncthreads();
    // i = (t*32 + cout)*32 + k
    for (int i = tid; i < 9216; i += 256) {
        const int k    = i & 31;
        const int cout = (i >> 5) & 31;
        const int t    = i >> 10;
        const int cin  = 16*(k & 1) + (k >> 1);
        const int src  = (cout*32 + cin)*9 + t;
        const float v1 = w1[src] / n1[cout];
        const float v2 = w2[src] / n2[cout];
        const _Float16 h1v = (_Float16)v1;
        const _Float16 h2v = (_Float16)v2;
        wn1hi[i] = h1v; wn1lo[i] = (_Float16)(v1 - (float)h1v);
        wn2hi[i] = h2v; wn2lo[i] = (_Float16)(v2 - (float)h2v);
    }
    for (int i = tid; i < 1024; i += 256) {
        const int cout = i >> 5;
        wn3[i] = w3[i] / n3[cout];
    }
    if (tid < 32) {
        float a1 = p1[tid]*0.1f, a2 = p2[tid]*0.1f, a3 = p3[tid]*0.1f;
        params[tid]      = a1*a1;
        params[32 + tid] = a2*a2;
        params[64 + tid] = a3*a3;
    }
    if (tid == 0) {
        params[96] = fabsf(q1[0])*0.01f;
        params[97] = fabsf(q2[0])*0.01f;
        params[98] = fabsf(q3[0])*0.01f;
    }
}

// ---------------------------------------------------------------------------
// Geometry: 16x16 output tile, halo 18x18 = 324 pixels. 512 threads = 8 waves;
// wave wv owns output rows 2wv..2wv+1 (acc[2][2], 16 regs).
// LDS record per pixel: 32 u32 (ch k packed hi|lo<<16) = 8 slots of 16B;
// physical slot = logical ^ (pix & 7)  -> all LDS traffic 2-way (free).
// MFMA lane map (verified r3-r6): A lane m16 -> pixel col, g4 -> K-octet;
// D: cout = cf*16+m16, col = 4*g4+reg, row = 2*wv+fr.
// ---------------------------------------------------------------------------
#define NPIX 324

// K loop, read-once-per-dj: load the 4 shared halo rows (hi+lo via v_perm)
// once, then loop di with streamed weights. 24 b128 LDS reads + 48 perms
// total (was 36 + 144). Live regs ~64 (acc16 + ah16 + al16 + w16).
__device__ __forceinline__ void kloop_mfma(
    const unsigned int* recs,
    const _Float16* __restrict__ wnhi, const _Float16* __restrict__ wnlo,
    f32x4 acc[2][2], int wv, int m16, int g4)
{
    #pragma unroll
    for (int dj = 0; dj < 3; ++dj) {
        f16x8 ah[4], al[4];
        #pragma unroll
        for (int rr = 0; rr < 4; ++rr) {
            const int pix = (2*wv + rr)*18 + m16 + dj;
            const int sw  = pix & 7;
            const uint4 r0 = *(const uint4*)(recs + pix*32 + ((2*g4    ) ^ sw)*4);
            const uint4 r1 = *(const uint4*)(recs + pix*32 + ((2*g4 + 1) ^ sw)*4);
            uint4 h, l;
            h.x = perm_hi(r0.x, r0.y); l.x = perm_lo(r0.x, r0.y);
            h.y = perm_hi(r0.z, r0.w); l.y = perm_lo(r0.z, r0.w);
            h.z = perm_hi(r1.x, r1.y); l.z = perm_lo(r1.x, r1.y);
            h.w = perm_hi(r1.z, r1.w); l.w = perm_lo(r1.z, r1.w);
            ah[rr] = *(const f16x8*)&h;
            al[rr] = *(const f16x8*)&l;
        }
        #pragma unroll
        for (int di = 0; di < 3; ++di) {
            f16x8 wh[2], wl[2];
            #pragma unroll
            for (int cf = 0; cf < 2; ++cf) {
                const int o = ((di*3 + dj)*32 + cf*16 + m16)*32 + g4*8;
                wh[cf] = *(const f16x8*)(wnhi + o);
                wl[cf] = *(const f16x8*)(wnlo + o);
            }
            #pragma unroll
            for (int fr = 0; fr < 2; ++fr)
                #pragma unroll
                for (int cf = 0; cf < 2; ++cf) {
                    acc[fr][cf] = __builtin_amdgcn_mfma_f32_16x16x32_f16(
                        ah[di + fr], wh[cf], acc[fr][cf], 0, 0, 0);
                    acc[fr][cf] = __builtin_amdgcn_mfma_f32_16x16x32_f16(
                        al[di + fr], wh[cf], acc[fr][cf], 0, 0, 0);
                    acc[fr][cf] = __builtin_amdgcn_mfma_f32_16x16x32_f16(
                        ah[di + fr], wl[cf], acc[fr][cf], 0, 0, 0);
                }
        }
    }
}

// ---------------------------------------------------------------------------
// Layer 1: x (fp32 NCHW) -> h1 packed records.
// Stage is pixel-major: lanes cover consecutive pixels of ONE channel plane
// per load -> coalesced 64-72B runs (r6 had 4-channel interleave = 4x64B).
// ---------------------------------------------------------------------------
__global__ __launch_bounds__(512, 6) void scs3x3_l1(
    const float* __restrict__ x,
    const _Float16* __restrict__ wnhi, const _Float16* __restrict__ wnlo,
    const float* __restrict__ peff, const float* __restrict__ qeffp,
    unsigned int* __restrict__ h1)
{
    __shared__ alignas(16) unsigned int recs[NPIX*32];   // 41472 B
    __shared__ float scratch4[4*NPIX];                   //  5184 B
    __shared__ float rden[256];                          //  1024 B

    const int tid   = threadIdx.x;
    const int tileR = blockIdx.x & 15;
    const int tileC = blockIdx.x >> 4;
    const int n     = blockIdx.y;
    const int lane  = tid & 63;
    const int wv    = tid >> 6;
    const int m16   = lane & 15;
    const int g4    = lane >> 4;

    const float* xin = x + (size_t)n * 32 * 65536;

    // ---- stage: pixel-major (p minor across lanes), split fp32 -> packed u32
    for (int i = tid; i < 4*NPIX; i += 512) {
        const int q = i / NPIX;          // channel octet 0..3
        const int p = i - q*NPIX;        // pixel (lane-consecutive)
        const int ro = p / 18, co = p - ro*18;
        const int gr = tileR*16 + ro - 1;
        const int gc = tileC*16 + co - 1;
        const bool ok = ((unsigned)gr < 256u) && ((unsigned)gc < 256u);
        const int base = gr*256 + gc;
        float s = 0.f;
        unsigned int pk[8];
        #pragma unroll
        for (int j = 0; j < 8; ++j) {
            const int k   = 8*q + j;
            const int cin = 16*(k & 1) + (k >> 1);
            const float v = ok ? xin[(size_t)cin*65536 + base] : 0.f;
            s += v*v;
            pk[j] = packsplit(v);
        }
        const int sw = p & 7;
        *(uint4*)(recs + p*32 + ((2*q    ) ^ sw)*4) = make_uint4(pk[0], pk[1], pk[2], pk[3]);
        *(uint4*)(recs + p*32 + ((2*q + 1) ^ sw)*4) = make_uint4(pk[4], pk[5], pk[6], pk[7]);
        scratch4[q*NPIX + p] = s;
    }
    __syncthreads();

    // ---- window sums -> rden
    if (tid < 256) {
        const int r = tid >> 4, c = tid & 15;
        float sq = 0.f;
        #pragma unroll
        for (int di = 0; di < 3; ++di)
            #pragma unroll
            for (int dc = 0; dc < 3; ++dc) {
                const int p = (r + di)*18 + c + dc;
                sq += scratch4[p] + scratch4[NPIX + p] + scratch4[2*NPIX + p] + scratch4[3*NPIX + p];
            }
        rden[tid] = 1.f / (sqrtf(sq + EPSF) + qeffp[0]);
    }
    __syncthreads();

    // ---- K loop
    f32x4 acc[2][2];
    #pragma unroll
    for (int fr = 0; fr < 2; ++fr)
        #pragma unroll
        for (int cf = 0; cf < 2; ++cf)
            acc[fr][cf] = (f32x4){0.f, 0.f, 0.f, 0.f};
    kloop_mfma(recs, wnhi, wnlo, acc, wv, m16, g4);

    // ---- epilogue: pow + packed record write (uint2: couts m16, m16+16)
    unsigned int* hq = h1 + (size_t)n * 65536 * 32;
    const float pe0 = peff[m16];
    const float pe1 = peff[16 + m16];
    #pragma unroll
    for (int fr = 0; fr < 2; ++fr) {
        const int r_loc = 2*wv + fr;
        const f32x4 rv = *(const f32x4*)(rden + r_loc*16 + 4*g4);
        const int gr = tileR*16 + r_loc;
        #pragma unroll
        for (int reg = 0; reg < 4; ++reg) {
            const int gc = tileC*16 + 4*g4 + reg;
            uint2 pk;
            pk.x = packsplit(fastpow_scs(acc[fr][0][reg] * rv[reg], pe0));
            pk.y = packsplit(fastpow_scs(acc[fr][1][reg] * rv[reg], pe1));
            *(uint2*)(hq + (size_t)(gr*256 + gc)*32 + 2*m16) = pk;
        }
    }
}

// ---------------------------------------------------------------------------
// Layer 2 + maxabs pool: h1 records -> out += pooled result (fp32 NCHW 128^2).
// Stage is a pure coalesced uint4 copy; s recomputed from packed values.
// ---------------------------------------------------------------------------
__global__ __launch_bounds__(512, 6) void scs3x3_l2(
    const unsigned int* __restrict__ h1,
    const _Float16* __restrict__ wnhi, const _Float16* __restrict__ wnlo,
    const float* __restrict__ peff, const float* __restrict__ qeffp,
    float* __restrict__ out)
{
    __shared__ alignas(16) unsigned int recs[NPIX*32];
    __shared__ float scratch4[4*NPIX];
    __shared__ float rden[256];

    const int tid   = threadIdx.x;
    const int tileR = blockIdx.x & 15;
    const int tileC = blockIdx.x >> 4;
    const int n     = blockIdx.y;
    const int lane  = tid & 63;
    const int wv    = tid >> 6;
    const int m16   = lane & 15;
    const int g4    = lane >> 4;

    const unsigned int* hb = h1 + (size_t)n * 65536 * 32;

    // ---- stage: coalesced copy + s from packed (hi+lo reconstruct)
    for (int i = tid; i < 4*NPIX; i += 512) {
        const int p = i >> 2, q = i & 3;
        const int ro = p / 18, co = p - ro*18;
        const int gr = tileR*16 + ro - 1;
        const int gc = tileC*16 + co - 1;
        uint4 d0 = make_uint4(0u,0u,0u,0u), d1 = make_uint4(0u,0u,0u,0u);
        if (((unsigned)gr < 256u) && ((unsigned)gc < 256u)) {
            const unsigned int* rec = hb + (size_t)(gr*256 + gc)*32 + 8*q;
            d0 = *(const uint4*)(rec);
            d1 = *(const uint4*)(rec + 4);
        }
        float s = 0.f;
        const unsigned int us[8] = {d0.x,d0.y,d0.z,d0.w,d1.x,d1.y,d1.z,d1.w};
        #pragma unroll
        for (int j = 0; j < 8; ++j) {
            const float v = h2f(us[j] & 0xffffu) + h2f(us[j] >> 16);
            s += v*v;
        }
        const int sw = p & 7;
        *(uint4*)(recs + p*32 + ((2*q    ) ^ sw)*4) = d0;
        *(uint4*)(recs + p*32 + ((2*q + 1) ^ sw)*4) = d1;
        scratch4[q*NPIX + p] = s;
    }
    __syncthreads();

    if (tid < 256) {
        const int r = tid >> 4, c = tid & 15;
        float sq = 0.f;
        #pragma unroll
        for (int di = 0; di < 3; ++di)
            #pragma unroll
            for (int dc = 0; dc < 3; ++dc) {
                const int p = (r + di)*18 + c + dc;
                sq += scratch4[p] + scratch4[NPIX + p] + scratch4[2*NPIX + p] + scratch4[3*NPIX + p];
            }
        rden[tid] = 1.f / (sqrtf(sq + EPSF) + qeffp[0]);
    }
    __syncthreads();

    // ---- K loop
    f32x4 acc[2][2];
    #pragma unroll
    for (int fr = 0; fr < 2; ++fr)
        #pragma unroll
        for (int cf = 0; cf < 2; ++cf)
            acc[fr][cf] = (f32x4){0.f, 0.f, 0.f, 0.f};
    kloop_mfma(recs, wnhi, wnlo, acc, wv, m16, g4);

    // ---- epilogue: 2x2 maxabs pool (rows fr=0,1; col pairs), pow, out +=
    const float pe0 = peff[m16];
    const float pe1 = peff[16 + m16];
    const f32x4 rv0 = *(const f32x4*)(rden + (2*wv    )*16 + 4*g4);
    const f32x4 rv1 = *(const f32x4*)(rden + (2*wv + 1)*16 + 4*g4);
    const int orow = tileR*8 + wv;
    const int ocol = tileC*8 + 2*g4;
    #pragma unroll
    for (int cf = 0; cf < 2; ++cf) {
        const int cout = cf*16 + m16;
        const float pe = cf ? pe1 : pe0;
        float o2[2];
        #pragma unroll
        for (int cp = 0; cp < 2; ++cp) {
            const float a0 = acc[0][cf][2*cp    ] * rv0[2*cp    ];
            const float a1 = acc[0][cf][2*cp + 1] * rv0[2*cp + 1];
            const float b0 = acc[1][cf][2*cp    ] * rv1[2*cp    ];
            const float b1 = acc[1][cf][2*cp + 1] * rv1[2*cp + 1];
            const float pos = fmaxf(fmaxf(a0, a1), fmaxf(b0, b1));
            const float neg = fmaxf(fmaxf(-a0, -a1), fmaxf(-b0, -b1));
            const float pooled = (pos >= neg) ? pos : -neg;
            o2[cp] = fastpow_scs(pooled, pe);
        }
        float2* po = (float2*)(out + (((size_t)n*32 + cout)*128 + orow)*128 + ocol);
        const float2 cur = *po;
        *po = make_float2(cur.x + o2[0], cur.y + o2[1]);
    }
}

// ---------------------------------------------------------------------------
// Residual branch: maxabs-pool x (2x2), SCS 1x1 conv (pure fp32), out = result.
// ---------------------------------------------------------------------------
__global__ __launch_bounds__(256) void pool_scs1x1_kernel(
    const float* __restrict__ x, const float* __restrict__ wn3,
    const float* __restrict__ peff, const float* __restrict__ qeffp,
    float* __restrict__ out)
{
    const int tid = threadIdx.x;
    const int col = tid & 127;
    const int row = blockIdx.x*2 + (tid >> 7);
    const int n   = blockIdx.y;

    const float* xb = x + (size_t)n*32*65536 + (size_t)(row*2)*256 + col*2;
    float px[32];
    float sq = 0.f;
    #pragma unroll
    for (int cin = 0; cin < 32; ++cin) {
        const float2 a = *(const float2*)(xb + (size_t)cin*65536);
        const float2 b = *(const float2*)(xb + (size_t)cin*65536 + 256);
        const float pos = fmaxf(fmaxf(a.x, a.y), fmaxf(b.x, b.y));
        const float neg = fmaxf(fmaxf(-a.x, -a.y), fmaxf(-b.x, -b.y));
        const float v = (pos >= neg) ? pos : -neg;
        px[cin] = v;
        sq += v*v;
    }
    const float qe    = qeffp[0];
    const float rdenv = 1.f / (sqrtf(sq + EPSF) + qe);

    #pragma unroll 4
    for (int cout = 0; cout < 32; ++cout) {
        const float* wr = wn3 + cout*32;   // wave-uniform -> s_load
        float acc = 0.f;
        #pragma unroll
        for (int cin = 0; cin < 32; ++cin)
            acc = fmaf(px[cin], wr[cin], acc);
        const float cs = acc * rdenv;
        const float res = fastpow_scs(cs, peff[cout]);
        const size_t oi = (((size_t)n*32 + cout)*128 + row)*128 + col;
        out[oi] = res;   // overwrite; scs3x3_l2 adds the main path afterwards
    }
}

// ---------------------------------------------------------------------------
extern "C" void kernel_launch(void* const* d_in, const int* in_sizes, int n_in,
                              void* d_out, int out_size, void* d_ws, size_t ws_size,
                              hipStream_t stream)
{
    (void)in_sizes; (void)n_in; (void)out_size;
    const float* x  = (const float*)d_in[0];
    const float* w1 = (const float*)d_in[1];
    const float* p1 = (const float*)d_in[2];
    const float* q1 = (const float*)d_in[3];
    const float* w2 = (const float*)d_in[4];
    const float* p2 = (const float*)d_in[5];
    const float* q2 = (const float*)d_in[6];
    const float* w3 = (const float*)d_in[7];
    const float* p3 = (const float*)d_in[8];
    const float* q3 = (const float*)d_in[9];

    char* wsb = (char*)d_ws;
    _Float16* wn1hi = (_Float16*)(wsb);          // 9216 f16 = 18432 B
    _Float16* wn1lo = (_Float16*)(wsb + 18432);
    _Float16* wn2hi = (_Float16*)(wsb + 36864);
    _Float16* wn2lo = (_Float16*)(wsb + 55296);
    float*    wn3   = (float*)(wsb + 73728);     // 1024 f32 = 4096 B
    float*    params= (float*)(wsb + 77824);     //  128 f32 =  512 B
    unsigned int* h1= (unsigned int*)(wsb + 78336);  // 32*65536*32 u32 = 268435456 B

    const size_t need = 78336 + (size_t)32*65536*32*4;
    if (ws_size < need) return;  // fail visibly rather than corrupt memory

    float* out = (float*)d_out;

    prep_kernel<<<1, 256, 0, stream>>>(w1,p1,q1, w2,p2,q2, w3,p3,q3,
                                       wn1hi, wn1lo, wn2hi, wn2lo, wn3, params);

    const dim3 grid(256, 32);   // 16x16 tiles of 16x16, 32 batches
    // layer 1: x -> h1 packed records
    scs3x3_l1<<<grid, 512, 0, stream>>>(x, wn1hi, wn1lo, params, params+96, h1);
    // residual branch: pool(x) -> 1x1 scs -> out  (overwrite)
    pool_scs1x1_kernel<<<dim3(64,32), 256, 0, stream>>>(x, wn3, params+64, params+98, out);
    // layer 2 + maxabs pool: h1 -> out += pooled
    scs3x3_l2<<<grid, 512, 0, stream>>>(h1, wn2hi, wn2lo, params+32, params+97, out);
}

// Round 8
// 462.406 us; speedup vs baseline: 2.8918x; 1.0531x over previous
//
#include <hip/hip_runtime.h>
#include <math.h>

#define EPSF 1e-12f

typedef _Float16 f16x8 __attribute__((ext_vector_type(8)));
typedef float f32x4 __attribute__((ext_vector_type(4)));

// sign(cs) * (|cs| + EPS)^pe with fast path for pe ~= 2.
__device__ __forceinline__ float fastpow_scs(float cs, float pe) {
    if (__builtin_fabsf(pe - 2.0f) < 1e-4f) {
        return cs * __builtin_fabsf(cs);
    }
    float m = __builtin_amdgcn_exp2f(pe * __builtin_amdgcn_logf(__builtin_fabsf(cs) + EPSF));
    return __builtin_copysignf(m, cs);
}

__device__ __forceinline__ float h2f(unsigned int bits16) {
    union { unsigned short u; _Float16 h; } z;
    z.u = (unsigned short)bits16;
    return (float)z.h;
}
__device__ __forceinline__ unsigned int pack2h(_Float16 a, _Float16 b) {
    union { _Float16 h[2]; unsigned int u; } z;
    z.h[0] = a; z.h[1] = b;
    return z.u;
}

// ---------------------------------------------------------------------------
// Prep: per-cout weight norms; split-fp16 weights (hi + residual lo) in
// [tap][cout][k] layout, K-order: k -> cin = 16*(k&1) + (k>>1)  (matches the
// record plane order: plane halfword k holds channel cin(k)).
// params: [0:32)=peff1 [32:64)=peff2 [64:96)=peff3 [96]=qe1 [97]=qe2 [98]=qe3
// ---------------------------------------------------------------------------
__global__ __launch_bounds__(256) void prep_kernel(
    const float* __restrict__ w1, const float* __restrict__ p1, const float* __restrict__ q1,
    const float* __restrict__ w2, const float* __restrict__ p2, const float* __restrict__ q2,
    const float* __restrict__ w3, const float* __restrict__ p3, const float* __restrict__ q3,
    _Float16* __restrict__ wn1hi, _Float16* __restrict__ wn1lo,
    _Float16* __restrict__ wn2hi, _Float16* __restrict__ wn2lo,
    float* __restrict__ wn3, float* __restrict__ params)
{
    __shared__ float n1[32], n2[32], n3[32];
    const int tid = threadIdx.x;
    if (tid < 32) {
        float s = 0.f;
        for (int i = 0; i < 288; ++i) { float v = w1[tid*288 + i]; s += v*v; }
        n1[tid] = sqrtf(s + EPSF);
    } else if (tid < 64) {
        const int c = tid - 32; float s = 0.f;
        for (int i = 0; i < 288; ++i) { float v = w2[c*288 + i]; s += v*v; }
        n2[c] = sqrtf(s + EPSF);
    } else if (tid < 96) {
        const int c = tid - 64; float s = 0.f;
        for (int i = 0; i < 32; ++i) { float v = w3[c*32 + i]; s += v*v; }
        n3[c] = sqrtf(s + EPSF);
    }
    __syncthreads();
    // i = (t*32 + cout)*32 + k
    for (int i = tid; i < 9216; i += 256) {
        const int k    = i & 31;
        const int cout = (i >> 5) & 31;
        const int t    = i >> 10;
        const int cin  = 16*(k & 1) + (k >> 1);
        const int src  = (cout*32 + cin)*9 + t;
        const float v1 = w1[src] / n1[cout];
        const float v2 = w2[src] / n2[cout];
        const _Float16 h1v = (_Float16)v1;
        const _Float16 h2v = (_Float16)v2;
        wn1hi[i] = h1v; wn1lo[i] = (_Float16)(v1 - (float)h1v);
        wn2hi[i] = h2v; wn2lo[i] = (_Float16)(v2 - (float)h2v);
    }
    for (int i = tid; i < 1024; i += 256) {
        const int cout = i >> 5;
        wn3[i] = w3[i] / n3[cout];
    }
    if (tid < 32) {
        float a1 = p1[tid]*0.1f, a2 = p2[tid]*0.1f, a3 = p3[tid]*0.1f;
        params[tid]      = a1*a1;
        params[32 + tid] = a2*a2;
        params[64 + tid] = a3*a3;
    }
    if (tid == 0) {
        params[96] = fabsf(q1[0])*0.01f;
        params[97] = fabsf(q2[0])*0.01f;
        params[98] = fabsf(q3[0])*0.01f;
    }
}

// ---------------------------------------------------------------------------
// FUSED L1+L2 kernel. 16x16 final-conv tile -> 8x8 pooled, one batch n.
// x halo: 20x20 = 400 records on a stride-20 linear grid (p = row*20+col).
// LDS record per pixel: 128 B = hi-plane (32 f16, slots 0-3) + lo-plane
// (slots 4-7); physical slot = logical ^ (pix & 7). NO packed-u32 / perms.
// L1: outputs the 18x18 h1 halo via LINEAR M-frags: frag f covers q-slots
// [16f, 16f+16) of the stride-20 grid; 24 frags (q in [0,384)), invalid
// slots (col>=18, row>=18, or out-of-image) get rden1=0 -> h1=0 (matches
// reference zero-padding). h1 records overwrite the x records in LDS.
// L2: row-frags as r7 (wave wv owns rows 2wv,2wv+1), pool, out +=.
// MFMA lane map (verified r3-r7): A lane m16 -> M(pixel), g4 -> K-octet;
// D: cout = cf*16+m16, M-col = 4*g4+reg.
// LDS 61.3 KB -> 2 blocks/CU.
// ---------------------------------------------------------------------------
#define REC_N 428   // 400 real + pad (L1 A-reads reach record 425)

__global__ __launch_bounds__(512, 4) void scs_fused(
    const float* __restrict__ x,
    const _Float16* __restrict__ w1hi, const _Float16* __restrict__ w1lo,
    const _Float16* __restrict__ w2hi, const _Float16* __restrict__ w2lo,
    const float* __restrict__ params,
    float* __restrict__ out)
{
    __shared__ alignas(16) unsigned int recs[REC_N*32];  // 54784 B
    __shared__ alignas(16) float scratch[1600];          //  6400 B (ss partials; later ss2 [0:400) + rden2 [400:656))
    __shared__ alignas(16) float rden1[384];             //  1536 B

    const int tid   = threadIdx.x;
    const int tileR = blockIdx.x & 15;
    const int tileC = blockIdx.x >> 4;
    const int n     = blockIdx.y;
    const int lane  = tid & 63;
    const int wv    = tid >> 6;
    const int m16   = lane & 15;
    const int g4    = lane >> 4;

    const float* xin = x + (size_t)n * 32 * 65536;

    // ---- phase 1: stage 20x20 x halo (hi/lo planes) + ss partials
    for (int i = tid; i < 1600; i += 512) {
        const int q = i / 400;           // channel octet 0..3
        const int p = i - q*400;         // pixel (lane-consecutive)
        const int ro = p / 20, co = p - ro*20;
        const int gr = tileR*16 + ro - 2;
        const int gc = tileC*16 + co - 2;
        const bool ok = ((unsigned)gr < 256u) && ((unsigned)gc < 256u);
        const int base = gr*256 + gc;
        float s = 0.f;
        f16x8 hi, lo;
        #pragma unroll
        for (int j = 0; j < 8; ++j) {
            const int k   = 8*q + j;
            const int cin = 16*(k & 1) + (k >> 1);
            const float v = ok ? xin[(size_t)cin*65536 + base] : 0.f;
            s += v*v;
            hi[j] = (_Float16)v;
            lo[j] = (_Float16)(v - (float)hi[j]);
        }
        const int sw = p & 7;
        *(f16x8*)(recs + p*32 + ((q    ) ^ sw)*4) = hi;
        *(f16x8*)(recs + p*32 + ((4 + q) ^ sw)*4) = lo;
        scratch[q*400 + p] = s;
    }
    for (int i = tid; i < (REC_N - 400)*32; i += 512) recs[400*32 + i] = 0u;
    __syncthreads();

    // ---- phase 2: rden1 for all 384 q-slots (0 for invalid/out-of-image)
    if (tid < 384) {
        const int r1 = tid / 20, c1 = tid - r1*20;
        const int hr = tileR*16 + r1 - 1;
        const int hc = tileC*16 + c1 - 1;
        float rd = 0.f;
        if (r1 < 18 && c1 < 18 && (unsigned)hr < 256u && (unsigned)hc < 256u) {
            float sq = 0.f;
            #pragma unroll
            for (int di = 0; di < 3; ++di)
                #pragma unroll
                for (int dj = 0; dj < 3; ++dj) {
                    const int p = (r1 + di)*20 + (c1 + dj);
                    sq += scratch[p] + scratch[400 + p] + scratch[800 + p] + scratch[1200 + p];
                }
            rd = 1.f / (sqrtf(sq + EPSF) + params[96]);
        }
        rden1[tid] = rd;
    }
    __syncthreads();

    // ---- phase 3: L1 kloop — wave wv owns frags 3wv..3wv+2 (24 total)
    f32x4 acc[3][2];
    #pragma unroll
    for (int fi = 0; fi < 3; ++fi)
        #pragma unroll
        for (int cf = 0; cf < 2; ++cf)
            acc[fi][cf] = (f32x4){0.f, 0.f, 0.f, 0.f};
    const int f0 = 3*wv;
    #pragma unroll
    for (int dj = 0; dj < 3; ++dj) {
        #pragma unroll
        for (int di = 0; di < 3; ++di) {
            f16x8 wh[2], wl[2];
            #pragma unroll
            for (int cf = 0; cf < 2; ++cf) {
                const int o = ((di*3 + dj)*32 + cf*16 + m16)*32 + g4*8;
                wh[cf] = *(const f16x8*)(w1hi + o);
                wl[cf] = *(const f16x8*)(w1lo + o);
            }
            #pragma unroll
            for (int fi = 0; fi < 3; ++fi) {
                const int p  = (f0 + fi)*16 + m16 + di*20 + dj;
                const int sw = p & 7;
                const f16x8 ah = *(const f16x8*)(recs + p*32 + ((g4    ) ^ sw)*4);
                const f16x8 al = *(const f16x8*)(recs + p*32 + ((4 + g4) ^ sw)*4);
                #pragma unroll
                for (int cf = 0; cf < 2; ++cf) {
                    acc[fi][cf] = __builtin_amdgcn_mfma_f32_16x16x32_f16(ah, wh[cf], acc[fi][cf], 0, 0, 0);
                    acc[fi][cf] = __builtin_amdgcn_mfma_f32_16x16x32_f16(al, wh[cf], acc[fi][cf], 0, 0, 0);
                    acc[fi][cf] = __builtin_amdgcn_mfma_f32_16x16x32_f16(ah, wl[cf], acc[fi][cf], 0, 0, 0);
                }
            }
        }
    }
    __syncthreads();   // all x-record reads complete

    // ---- phase 4: pow + write h1 records (planes) over the x records
    {
        const float pe0 = params[m16];
        const float pe1 = params[16 + m16];
        #pragma unroll
        for (int fi = 0; fi < 3; ++fi) {
            #pragma unroll
            for (int reg = 0; reg < 4; ++reg) {
                const int q  = (f0 + fi)*16 + 4*g4 + reg;
                const float rv = rden1[q];
                const float r0 = fastpow_scs(acc[fi][0][reg] * rv, pe0);
                const float r1 = fastpow_scs(acc[fi][1][reg] * rv, pe1);
                const _Float16 h0 = (_Float16)r0, h1f = (_Float16)r1;
                const _Float16 l0 = (_Float16)(r0 - (float)h0);
                const _Float16 l1 = (_Float16)(r1 - (float)h1f);
                // couts m16, m16+16 -> k = 2*m16, 2*m16+1 -> plane word m16
                const int sw = q & 7;
                recs[q*32 + (((m16 >> 2)    ) ^ sw)*4 + (m16 & 3)] = pack2h(h0, h1f);
                recs[q*32 + ((4 + (m16 >> 2)) ^ sw)*4 + (m16 & 3)] = pack2h(l0, l1);
            }
        }
    }
    __syncthreads();

    // ---- phase 5: ss2 per valid h1 pixel (18x18) -> scratch[0:400)
    for (int i = tid; i < 324; i += 512) {
        const int r1 = i / 18, c1 = i - r1*18;
        const int q  = r1*20 + c1;
        const int sw = q & 7;
        float s = 0.f;
        #pragma unroll
        for (int sl = 0; sl < 4; ++sl) {
            const uint4 qh = *(const uint4*)(recs + q*32 + ((sl    ) ^ sw)*4);
            const uint4 ql = *(const uint4*)(recs + q*32 + ((4 + sl) ^ sw)*4);
            const unsigned int hs[4] = {qh.x, qh.y, qh.z, qh.w};
            const unsigned int ls[4] = {ql.x, ql.y, ql.z, ql.w};
            #pragma unroll
            for (int e = 0; e < 4; ++e) {
                const float va = h2f(hs[e] & 0xffffu) + h2f(ls[e] & 0xffffu);
                const float vb = h2f(hs[e] >> 16)     + h2f(ls[e] >> 16);
                s += va*va + vb*vb;
            }
        }
        scratch[q] = s;
    }
    __syncthreads();

    // ---- phase 6: rden2 for the 16x16 outputs -> scratch[400:656)
    if (tid < 256) {
        const int r = tid >> 4, c = tid & 15;
        float sq = 0.f;
        #pragma unroll
        for (int di = 0; di < 3; ++di)
            #pragma unroll
            for (int dj = 0; dj < 3; ++dj)
                sq += scratch[(r + di)*20 + (c + dj)];
        scratch[400 + tid] = 1.f / (sqrtf(sq + EPSF) + params[97]);
    }
    __syncthreads();

    // ---- phase 7: L2 kloop — wave wv owns output rows 2wv, 2wv+1
    f32x4 acc2[2][2];
    #pragma unroll
    for (int fr = 0; fr < 2; ++fr)
        #pragma unroll
        for (int cf = 0; cf < 2; ++cf)
            acc2[fr][cf] = (f32x4){0.f, 0.f, 0.f, 0.f};
    #pragma unroll
    for (int dj = 0; dj < 3; ++dj) {
        f16x8 ah[4], al[4];
        #pragma unroll
        for (int rr = 0; rr < 4; ++rr) {
            const int p  = (2*wv + rr)*20 + m16 + dj;
            const int sw = p & 7;
            ah[rr] = *(const f16x8*)(recs + p*32 + ((g4    ) ^ sw)*4);
            al[rr] = *(const f16x8*)(recs + p*32 + ((4 + g4) ^ sw)*4);
        }
        #pragma unroll
        for (int di = 0; di < 3; ++di) {
            f16x8 wh[2], wl[2];
            #pragma unroll
            for (int cf = 0; cf < 2; ++cf) {
                const int o = ((di*3 + dj)*32 + cf*16 + m16)*32 + g4*8;
                wh[cf] = *(const f16x8*)(w2hi + o);
                wl[cf] = *(const f16x8*)(w2lo + o);
            }
            #pragma unroll
            for (int fr = 0; fr < 2; ++fr)
                #pragma unroll
                for (int cf = 0; cf < 2; ++cf) {
                    acc2[fr][cf] = __builtin_amdgcn_mfma_f32_16x16x32_f16(ah[di + fr], wh[cf], acc2[fr][cf], 0, 0, 0);
                    acc2[fr][cf] = __builtin_amdgcn_mfma_f32_16x16x32_f16(al[di + fr], wh[cf], acc2[fr][cf], 0, 0, 0);
                    acc2[fr][cf] = __builtin_amdgcn_mfma_f32_16x16x32_f16(ah[di + fr], wl[cf], acc2[fr][cf], 0, 0, 0);
                }
        }
    }

    // ---- phase 8: 2x2 maxabs pool, pow after pool, out += (residual there)
    {
        const float pe0 = params[32 + m16];
        const float pe1 = params[48 + m16];
        const float* rden2 = scratch + 400;
        const f32x4 rv0 = *(const f32x4*)(rden2 + (2*wv    )*16 + 4*g4);
        const f32x4 rv1 = *(const f32x4*)(rden2 + (2*wv + 1)*16 + 4*g4);
        const int orow = tileR*8 + wv;
        const int ocol = tileC*8 + 2*g4;
        #pragma unroll
        for (int cf = 0; cf < 2; ++cf) {
            const int cout = cf*16 + m16;
            const float pe = cf ? pe1 : pe0;
            float o2[2];
            #pragma unroll
            for (int cp = 0; cp < 2; ++cp) {
                const float a0 = acc2[0][cf][2*cp    ] * rv0[2*cp    ];
                const float a1 = acc2[0][cf][2*cp + 1] * rv0[2*cp + 1];
                const float b0 = acc2[1][cf][2*cp    ] * rv1[2*cp    ];
                const float b1 = acc2[1][cf][2*cp + 1] * rv1[2*cp + 1];
                const float pos = fmaxf(fmaxf(a0, a1), fmaxf(b0, b1));
                const float neg = fmaxf(fmaxf(-a0, -a1), fmaxf(-b0, -b1));
                const float pooled = (pos >= neg) ? pos : -neg;
                o2[cp] = fastpow_scs(pooled, pe);
            }
            float2* po = (float2*)(out + (((size_t)n*32 + cout)*128 + orow)*128 + ocol);
            const float2 cur = *po;
            *po = make_float2(cur.x + o2[0], cur.y + o2[1]);
        }
    }
}

// ---------------------------------------------------------------------------
// Residual branch: maxabs-pool x (2x2), SCS 1x1 conv (pure fp32), out = result.
// ---------------------------------------------------------------------------
__global__ __launch_bounds__(256) void pool_scs1x1_kernel(
    const float* __restrict__ x, const float* __restrict__ wn3,
    const float* __restrict__ peff, const float* __restrict__ qeffp,
    float* __restrict__ out)
{
    const int tid = threadIdx.x;
    const int col = tid & 127;
    const int row = blockIdx.x*2 + (tid >> 7);
    const int n   = blockIdx.y;

    const float* xb = x + (size_t)n*32*65536 + (size_t)(row*2)*256 + col*2;
    float px[32];
    float sq = 0.f;
    #pragma unroll
    for (int cin = 0; cin < 32; ++cin) {
        const float2 a = *(const float2*)(xb + (size_t)cin*65536);
        const float2 b = *(const float2*)(xb + (size_t)cin*65536 + 256);
        const float pos = fmaxf(fmaxf(a.x, a.y), fmaxf(b.x, b.y));
        const float neg = fmaxf(fmaxf(-a.x, -a.y), fmaxf(-b.x, -b.y));
        const float v = (pos >= neg) ? pos : -neg;
        px[cin] = v;
        sq += v*v;
    }
    const float qe    = qeffp[0];
    const float rdenv = 1.f / (sqrtf(sq + EPSF) + qe);

    #pragma unroll 4
    for (int cout = 0; cout < 32; ++cout) {
        const float* wr = wn3 + cout*32;   // wave-uniform -> s_load
        float acc = 0.f;
        #pragma unroll
        for (int cin = 0; cin < 32; ++cin)
            acc = fmaf(px[cin], wr[cin], acc);
        const float cs = acc * rdenv;
        const float res = fastpow_scs(cs, peff[cout]);
        const size_t oi = (((size_t)n*32 + cout)*128 + row)*128 + col;
        out[oi] = res;   // overwrite; scs_fused adds the main path afterwards
    }
}

// ---------------------------------------------------------------------------
extern "C" void kernel_launch(void* const* d_in, const int* in_sizes, int n_in,
                              void* d_out, int out_size, void* d_ws, size_t ws_size,
                              hipStream_t stream)
{
    (void)in_sizes; (void)n_in; (void)out_size;
    const float* x  = (const float*)d_in[0];
    const float* w1 = (const float*)d_in[1];
    const float* p1 = (const float*)d_in[2];
    const float* q1 = (const float*)d_in[3];
    const float* w2 = (const float*)d_in[4];
    const float* p2 = (const float*)d_in[5];
    const float* q2 = (const float*)d_in[6];
    const float* w3 = (const float*)d_in[7];
    const float* p3 = (const float*)d_in[8];
    const float* q3 = (const float*)d_in[9];

    char* wsb = (char*)d_ws;
    _Float16* wn1hi = (_Float16*)(wsb);          // 9216 f16 = 18432 B
    _Float16* wn1lo = (_Float16*)(wsb + 18432);
    _Float16* wn2hi = (_Float16*)(wsb + 36864);
    _Float16* wn2lo = (_Float16*)(wsb + 55296);
    float*    wn3   = (float*)(wsb + 73728);     // 1024 f32 = 4096 B
    float*    params= (float*)(wsb + 77824);     //  128 f32 =  512 B

    if (ws_size < (size_t)78336) return;  // fail visibly rather than corrupt memory

    float* out = (float*)d_out;

    prep_kernel<<<1, 256, 0, stream>>>(w1,p1,q1, w2,p2,q2, w3,p3,q3,
                                       wn1hi, wn1lo, wn2hi, wn2lo, wn3, params);

    // residual branch first: out = residual(pool(x))
    pool_scs1x1_kernel<<<dim3(64,32), 256, 0, stream>>>(x, wn3, params+64, params+98, out);
    // fused L1+L2+pool: out += main path (h1 never leaves LDS)
    scs_fused<<<dim3(256,32), 512, 0, stream>>>(x, wn1hi, wn1lo, wn2hi, wn2lo, params, out);
}